// Round 2
// baseline (603.402 us; speedup 1.0000x reference)
//
#include <hip/hip_runtime.h>
#include <hip/hip_bf16.h>
#include <stdint.h>

typedef __bf16 bf16_t;
typedef __bf16 bf16x8 __attribute__((ext_vector_type(8)));
typedef __bf16 bf16x4v __attribute__((ext_vector_type(4)));
typedef float f32x4 __attribute__((ext_vector_type(4)));

#define DEV __device__ __forceinline__

static constexpr int B_ = 2, S_ = 4096, E_ = 768, H_ = 12, D_ = 64;
static constexpr int WINDOW_ = 128;
static constexpr float QSCALE = 0.125f * 1.44269504088896f;  // fold log2(e): softmax via exp2
static constexpr float THR = 11.5f;                          // defer-max threshold (log2 domain)

// ---------- async 16B global -> LDS ----------
DEV void gload_lds16(const void* g, void* l) {
    __builtin_amdgcn_global_load_lds(
        (const __attribute__((address_space(1))) uint32_t*)g,
        (__attribute__((address_space(3))) uint32_t*)l, 16, 0, 0);
}

// ---------- fp32 -> bf16 convert ----------
__global__ void k_cvt(const float* __restrict__ in, bf16_t* __restrict__ out, int n) {
    int i = (blockIdx.x * blockDim.x + threadIdx.x) * 4;
    if (i < n) {
        float4 v = *(const float4*)(in + i);
        bf16x4v o;
        o[0] = (bf16_t)v.x; o[1] = (bf16_t)v.y; o[2] = (bf16_t)v.z; o[3] = (bf16_t)v.w;
        *(bf16x4v*)(out + i) = o;
    }
}

// ---------- NT GEMM: C[m][n] = sum_k A[m][k] * Bw[n][k] + bias[n] ----------
// EPI 0: scatter q (scaled, exp2-domain) / k into [B,H,S,D]; v directly into vt [B,H,D,S]
// EPI 1: fp32 output [M][N]
template<int EPI>
__global__ void k_gemm(const bf16_t* __restrict__ A, const bf16_t* __restrict__ Bw,
                       const float* __restrict__ bias,
                       bf16_t* __restrict__ qb, bf16_t* __restrict__ kb, bf16_t* __restrict__ vtb,
                       float* __restrict__ outf,
                       int M, int N, int K, int mtiles) {
    __shared__ bf16_t As[128 * 64];
    __shared__ bf16_t Bs[128 * 64];
    int bid = blockIdx.x;
    int tm = bid % mtiles, tn = bid / mtiles;
    int m0 = tm * 128, n0 = tn * 128;
    int t = threadIdx.x;
    int lane = t & 63, wid = t >> 6;
    int l15 = lane & 15, l4 = lane >> 4;
    int wm = (wid & 1) * 64, wn = (wid >> 1) * 64;

    f32x4 acc[4][4];
#pragma unroll
    for (int i = 0; i < 4; ++i)
#pragma unroll
        for (int j = 0; j < 4; ++j) acc[i][j] = f32x4{0.f, 0.f, 0.f, 0.f};

    for (int kt = 0; kt < K; kt += 64) {
        __syncthreads();
#pragma unroll
        for (int c = 0; c < 4; ++c) {
            int idx = t + 256 * c;
            int row = idx >> 3, part = idx & 7;
            int kc = 8 * (part ^ (row & 7));
            gload_lds16(A + (long)(m0 + row) * K + kt + kc, (char*)As + idx * 16);
            gload_lds16(Bw + (long)(n0 + row) * K + kt + kc, (char*)Bs + idx * 16);
        }
        __syncthreads();
#pragma unroll
        for (int kk = 0; kk < 2; ++kk) {
            bf16x8 af[4], bfr[4];
#pragma unroll
            for (int i = 0; i < 4; ++i) {
                int row = wm + i * 16 + l15;
                int off = row * 128 + ((16 * (kk * 4 + l4)) ^ ((row & 7) << 4));
                af[i] = *(const bf16x8*)((const char*)As + off);
                int rowb = wn + i * 16 + l15;
                int offb = rowb * 128 + ((16 * (kk * 4 + l4)) ^ ((rowb & 7) << 4));
                bfr[i] = *(const bf16x8*)((const char*)Bs + offb);
            }
#pragma unroll
            for (int i = 0; i < 4; ++i)
#pragma unroll
                for (int j = 0; j < 4; ++j)
                    acc[i][j] = __builtin_amdgcn_mfma_f32_16x16x32_bf16(af[i], bfr[j], acc[i][j], 0, 0, 0);
        }
    }

#pragma unroll
    for (int i = 0; i < 4; ++i) {
#pragma unroll
        for (int j = 0; j < 4; ++j) {
            int n = n0 + wn + j * 16 + l15;
            float bv = bias[n];
            int mbase = m0 + wm + i * 16 + l4 * 4;
            if (EPI == 0) {
                int sel = n / 768, nn = n % 768;
                int h = nn >> 6, d = nn & 63;
                int b = mbase >> 12, s = mbase & 4095;
                if (sel == 2) {
                    bf16x4v pk;
#pragma unroll
                    for (int r = 0; r < 4; ++r) pk[r] = (bf16_t)(acc[i][j][r] + bv);
                    *(bf16x4v*)(vtb + ((long)(b * H_ + h) * D_ + d) * S_ + s) = pk;
                } else {
                    long o = ((long)(b * H_ + h) * S_ + s) * D_ + d;
#pragma unroll
                    for (int r = 0; r < 4; ++r) {
                        float v = acc[i][j][r] + bv;
                        if (sel == 0) qb[o + (long)r * D_] = (bf16_t)(v * QSCALE);
                        else          kb[o + (long)r * D_] = (bf16_t)v;
                    }
                }
            } else {
#pragma unroll
                for (int r = 0; r < 4; ++r)
                    outf[(long)(mbase + r) * 768 + n] = acc[i][j][r] + bv;
            }
        }
    }
}

// ---------- attention: QBLK=128 (4 waves x 32 q), KVBLK=128 ----------
__global__ __launch_bounds__(256, 3)
void k_attn(const bf16_t* __restrict__ q, const bf16_t* __restrict__ k,
            const bf16_t* __restrict__ vt, bf16_t* __restrict__ ao) {
    __shared__ bf16_t Ks[128 * 64];    // [key][d] swizzled, 128B rows
    __shared__ bf16_t Vs[64 * 128];    // [d][key] swizzled, 256B rows
    __shared__ bf16_t Ps[4][16 * 128]; // per-wave [q][key] swizzled, 256B rows
    int bid = blockIdx.x;
    int bh = bid >> 5, qt = bid & 31;
    int q0 = qt * 128;
    int b = bh / H_, h = bh % H_;
    int t = threadIdx.x, lane = t & 63, wid = t >> 6;
    int l15 = lane & 15, l4 = lane >> 4;

    const bf16_t* qp = q + (long)bh * S_ * D_;
    const bf16_t* kp = k + (long)bh * S_ * D_;
    const bf16_t* vp = vt + (long)bh * D_ * S_;
    int wqb = q0 + wid * 32;

    bf16x8 qf[2][2];
#pragma unroll
    for (int g = 0; g < 2; ++g) {
        int row = wqb + g * 16 + l15;
        qf[g][0] = *(const bf16x8*)(qp + (long)row * 64 + 8 * l4);
        qf[g][1] = *(const bf16x8*)(qp + (long)row * 64 + 32 + 8 * l4);
    }

    f32x4 o[2][4];
    float m[2][4], sum[2][4];
#pragma unroll
    for (int g = 0; g < 2; ++g)
#pragma unroll
        for (int ns = 0; ns < 4; ++ns) o[g][ns] = f32x4{0.f, 0.f, 0.f, 0.f};
#pragma unroll
    for (int g = 0; g < 2; ++g)
#pragma unroll
        for (int r = 0; r < 4; ++r) { m[g][r] = -1e30f; sum[g][r] = 0.f; }

    bf16_t* pw = &Ps[wid][0];

    for (int kt = 0; kt < 32; ++kt) {
        int k0 = kt << 7;
        if (k0 == q0) continue;  // 128x128 diagonal tile fully banned (block-uniform)
        bool maskt = (k0 == q0 - 128) || (k0 == q0 + 128);

        __syncthreads();
#pragma unroll
        for (int c = 0; c < 4; ++c) {
            int idx = t + 256 * c;
            int krow = idx >> 3, kpart = idx & 7;
            gload_lds16(kp + (long)(k0 + krow) * 64 + 8 * (kpart ^ (krow & 7)),
                        (char*)Ks + idx * 16);
            int vrow = idx >> 4, vpart = idx & 15;
            gload_lds16(vp + (long)vrow * S_ + k0 + 8 * (vpart ^ (vrow & 7)),
                        (char*)Vs + idx * 16);
        }
        __syncthreads();

        // QK^T for both q-halves, sharing K fragments
        f32x4 s[2][8];
#pragma unroll
        for (int ks = 0; ks < 8; ++ks) { s[0][ks] = f32x4{0,0,0,0}; s[1][ks] = f32x4{0,0,0,0}; }
#pragma unroll
        for (int ks = 0; ks < 8; ++ks) {
            int row = ks * 16 + l15;
#pragma unroll
            for (int kk = 0; kk < 2; ++kk) {
                bf16x8 kf = *(const bf16x8*)((const char*)Ks + row * 128 +
                                             ((16 * (kk * 4 + l4)) ^ ((row & 7) << 4)));
                s[0][ks] = __builtin_amdgcn_mfma_f32_16x16x32_bf16(qf[0][kk], kf, s[0][ks], 0, 0, 0);
                s[1][ks] = __builtin_amdgcn_mfma_f32_16x16x32_bf16(qf[1][kk], kf, s[1][ks], 0, 0, 0);
            }
        }

#pragma unroll
        for (int g = 0; g < 2; ++g) {
            if (maskt) {
                int iq = wqb + g * 16 + l4 * 4;
#pragma unroll
                for (int ks = 0; ks < 8; ++ks) {
                    int j = k0 + ks * 16 + l15;
#pragma unroll
                    for (int r = 0; r < 4; ++r) {
                        int dd = iq + r - j; int ad = dd < 0 ? -dd : dd;
                        if (ad <= WINDOW_) s[g][ks][r] = -1e30f;
                    }
                }
            }
            // per-lane local max over the 8 ks-fragments
            float lm[4];
#pragma unroll
            for (int r = 0; r < 4; ++r) {
                float a0 = fmaxf(fmaxf(s[g][0][r], s[g][1][r]), fmaxf(s[g][2][r], s[g][3][r]));
                float a1 = fmaxf(fmaxf(s[g][4][r], s[g][5][r]), fmaxf(s[g][6][r], s[g][7][r]));
                lm[r] = fmaxf(a0, a1);
            }
            int ex = (lm[0] > m[g][0] + THR) | (lm[1] > m[g][1] + THR) |
                     (lm[2] > m[g][2] + THR) | (lm[3] > m[g][3] + THR);
            if (__any(ex)) {   // rescale path: rare after first tile
#pragma unroll
                for (int r = 0; r < 4; ++r) {
                    float tmv = lm[r];
                    tmv = fmaxf(tmv, __shfl_xor(tmv, 1));
                    tmv = fmaxf(tmv, __shfl_xor(tmv, 2));
                    tmv = fmaxf(tmv, __shfl_xor(tmv, 4));
                    tmv = fmaxf(tmv, __shfl_xor(tmv, 8));
                    float mn = fmaxf(m[g][r], tmv);
                    float f = exp2f(m[g][r] - mn);
                    m[g][r] = mn;
                    sum[g][r] *= f;
                    o[g][0][r] *= f; o[g][1][r] *= f; o[g][2][r] *= f; o[g][3][r] *= f;
                }
            }
            float ls[4] = {0.f, 0.f, 0.f, 0.f};
#pragma unroll
            for (int ks = 0; ks < 8; ++ks)
#pragma unroll
                for (int r = 0; r < 4; ++r) {
                    float p = exp2f(s[g][ks][r] - m[g][r]);
                    s[g][ks][r] = p;
                    ls[r] += p;
                }
#pragma unroll
            for (int r = 0; r < 4; ++r) {
                float v = ls[r];
                v += __shfl_xor(v, 1); v += __shfl_xor(v, 2);
                v += __shfl_xor(v, 4); v += __shfl_xor(v, 8);
                sum[g][r] += v;
            }
            // P -> LDS (wave-private, swizzled [q][key])
#pragma unroll
            for (int ks = 0; ks < 8; ++ks)
#pragma unroll
                for (int r = 0; r < 4; ++r) {
                    int qr = l4 * 4 + r;
                    int byteoff = qr * 256 + ((2 * (ks * 16 + l15)) ^ ((qr & 7) << 4));
                    *(bf16_t*)((char*)pw + byteoff) = (bf16_t)s[g][ks][r];
                }
            asm volatile("s_waitcnt lgkmcnt(0)" ::: "memory");
            __builtin_amdgcn_sched_barrier(0);
            // PV
            bf16x8 pf[4];
#pragma unroll
            for (int kk = 0; kk < 4; ++kk)
                pf[kk] = *(const bf16x8*)((const char*)pw + l15 * 256 +
                                          ((16 * (kk * 4 + l4)) ^ ((l15 & 7) << 4)));
#pragma unroll
            for (int ns = 0; ns < 4; ++ns) {
                int drow = ns * 16 + l15;
#pragma unroll
                for (int kk = 0; kk < 4; ++kk) {
                    bf16x8 vf = *(const bf16x8*)((const char*)Vs + drow * 256 +
                                                 ((16 * (kk * 4 + l4)) ^ ((drow & 7) << 4)));
                    o[g][ns] = __builtin_amdgcn_mfma_f32_16x16x32_bf16(pf[kk], vf, o[g][ns], 0, 0, 0);
                }
            }
        }
    }

    // finalize + write [B,S,E] bf16
#pragma unroll
    for (int g = 0; g < 2; ++g) {
        float inv[4];
#pragma unroll
        for (int r = 0; r < 4; ++r) inv[r] = 1.0f / sum[g][r];
#pragma unroll
        for (int ns = 0; ns < 4; ++ns)
#pragma unroll
            for (int r = 0; r < 4; ++r) {
                int srow = wqb + g * 16 + l4 * 4 + r;
                int e = h * 64 + ns * 16 + l15;
                ao[((long)b * S_ + srow) * E_ + e] = (bf16_t)(o[g][ns][r] * inv[r]);
            }
    }
}

extern "C" void kernel_launch(void* const* d_in, const int* in_sizes, int n_in,
                              void* d_out, int out_size, void* d_ws, size_t ws_size,
                              hipStream_t stream) {
    const float* x     = (const float*)d_in[0];
    const float* w_in  = (const float*)d_in[1];
    const float* b_in  = (const float*)d_in[2];
    const float* w_out = (const float*)d_in[3];
    const float* b_out = (const float*)d_in[4];
    float* out = (float*)d_out;

    char* ws = (char*)d_ws;
    bf16_t* xb  = (bf16_t*)(ws + 0);          // 12582912 (reused as attn-out)
    bf16_t* wib = (bf16_t*)(ws + 12582912);   // 3538944
    bf16_t* wob = (bf16_t*)(ws + 16121856);   // 1179648
    bf16_t* qb  = (bf16_t*)(ws + 17301504);   // 12582912
    bf16_t* kb  = (bf16_t*)(ws + 29884416);   // 12582912
    bf16_t* vtb = (bf16_t*)(ws + 42467328);   // 12582912
    bf16_t* ao  = xb;

    k_cvt<<<6144, 256, 0, stream>>>(x, xb, 6291456);
    k_cvt<<<1728, 256, 0, stream>>>(w_in, wib, 1769472);
    k_cvt<<<576, 256, 0, stream>>>(w_out, wob, 589824);

    // QKV projection: M=8192, N=2304, K=768 (v written pre-transposed)
    k_gemm<0><<<64 * 18, 256, 0, stream>>>(xb, wib, b_in, qb, kb, vtb, nullptr,
                                           8192, 2304, 768, 64);
    k_attn<<<24 * 32, 256, 0, stream>>>(qb, kb, vtb, ao);
    // out projection: M=8192, N=768, K=768
    k_gemm<1><<<64 * 6, 256, 0, stream>>>(ao, wob, b_out, nullptr, nullptr, nullptr, out,
                                          8192, 768, 768, 64);
}

// Round 3
// 388.451 us; speedup vs baseline: 1.5534x; 1.5534x over previous
//
#include <hip/hip_runtime.h>
#include <hip/hip_bf16.h>
#include <stdint.h>

typedef __bf16 bf16_t;
typedef __bf16 bf16x8 __attribute__((ext_vector_type(8)));
typedef __bf16 bf16x4v __attribute__((ext_vector_type(4)));
typedef float f32x4 __attribute__((ext_vector_type(4)));

#define DEV __device__ __forceinline__

static constexpr int B_ = 2, S_ = 4096, E_ = 768, H_ = 12, D_ = 64;
static constexpr int WINDOW_ = 128;
static constexpr float QSCALE = 0.125f * 1.44269504088896f;  // fold log2(e): softmax via exp2
static constexpr float THR = 11.5f;                          // defer-max threshold (log2 domain)

// ---------- async 16B global -> LDS ----------
DEV void gload_lds16(const void* g, void* l) {
    __builtin_amdgcn_global_load_lds(
        (const __attribute__((address_space(1))) uint32_t*)g,
        (__attribute__((address_space(3))) uint32_t*)l, 16, 0, 0);
}

// ---------- fp32 -> bf16 convert ----------
__global__ void k_cvt(const float* __restrict__ in, bf16_t* __restrict__ out, int n) {
    int i = (blockIdx.x * blockDim.x + threadIdx.x) * 4;
    if (i < n) {
        float4 v = *(const float4*)(in + i);
        bf16x4v o;
        o[0] = (bf16_t)v.x; o[1] = (bf16_t)v.y; o[2] = (bf16_t)v.z; o[3] = (bf16_t)v.w;
        *(bf16x4v*)(out + i) = o;
    }
}

// ---------- NT GEMM: C[m][n] = sum_k A[m][k] * Bw[n][k] + bias[n] ----------
// EPI 0: scatter q (scaled, exp2-domain) / k into [B,H,S,D]; v directly into vt [B,H,D,S]
// EPI 1: fp32 output [M][N]
template<int EPI>
__global__ void k_gemm(const bf16_t* __restrict__ A, const bf16_t* __restrict__ Bw,
                       const float* __restrict__ bias,
                       bf16_t* __restrict__ qb, bf16_t* __restrict__ kb, bf16_t* __restrict__ vtb,
                       float* __restrict__ outf,
                       int M, int N, int K, int mtiles) {
    __shared__ bf16_t As[128 * 64];
    __shared__ bf16_t Bs[128 * 64];
    int bid = blockIdx.x;
    int tm = bid % mtiles, tn = bid / mtiles;
    int m0 = tm * 128, n0 = tn * 128;
    int t = threadIdx.x;
    int lane = t & 63, wid = t >> 6;
    int l15 = lane & 15, l4 = lane >> 4;
    int wm = (wid & 1) * 64, wn = (wid >> 1) * 64;

    f32x4 acc[4][4];
#pragma unroll
    for (int i = 0; i < 4; ++i)
#pragma unroll
        for (int j = 0; j < 4; ++j) acc[i][j] = f32x4{0.f, 0.f, 0.f, 0.f};

    for (int kt = 0; kt < K; kt += 64) {
        __syncthreads();
#pragma unroll
        for (int c = 0; c < 4; ++c) {
            int idx = t + 256 * c;
            int row = idx >> 3, part = idx & 7;
            int kc = 8 * (part ^ (row & 7));
            gload_lds16(A + (long)(m0 + row) * K + kt + kc, (char*)As + idx * 16);
            gload_lds16(Bw + (long)(n0 + row) * K + kt + kc, (char*)Bs + idx * 16);
        }
        __syncthreads();
#pragma unroll
        for (int kk = 0; kk < 2; ++kk) {
            bf16x8 af[4], bfr[4];
#pragma unroll
            for (int i = 0; i < 4; ++i) {
                int row = wm + i * 16 + l15;
                int off = row * 128 + ((16 * (kk * 4 + l4)) ^ ((row & 7) << 4));
                af[i] = *(const bf16x8*)((const char*)As + off);
                int rowb = wn + i * 16 + l15;
                int offb = rowb * 128 + ((16 * (kk * 4 + l4)) ^ ((rowb & 7) << 4));
                bfr[i] = *(const bf16x8*)((const char*)Bs + offb);
            }
#pragma unroll
            for (int i = 0; i < 4; ++i)
#pragma unroll
                for (int j = 0; j < 4; ++j)
                    acc[i][j] = __builtin_amdgcn_mfma_f32_16x16x32_bf16(af[i], bfr[j], acc[i][j], 0, 0, 0);
        }
    }

#pragma unroll
    for (int i = 0; i < 4; ++i) {
#pragma unroll
        for (int j = 0; j < 4; ++j) {
            int n = n0 + wn + j * 16 + l15;
            float bv = bias[n];
            int mbase = m0 + wm + i * 16 + l4 * 4;
            if (EPI == 0) {
                int sel = n / 768, nn = n % 768;
                int h = nn >> 6, d = nn & 63;
                int b = mbase >> 12, s = mbase & 4095;
                if (sel == 2) {
                    bf16x4v pk;
#pragma unroll
                    for (int r = 0; r < 4; ++r) pk[r] = (bf16_t)(acc[i][j][r] + bv);
                    *(bf16x4v*)(vtb + ((long)(b * H_ + h) * D_ + d) * S_ + s) = pk;
                } else {
                    long o = ((long)(b * H_ + h) * S_ + s) * D_ + d;
#pragma unroll
                    for (int r = 0; r < 4; ++r) {
                        float v = acc[i][j][r] + bv;
                        if (sel == 0) qb[o + (long)r * D_] = (bf16_t)(v * QSCALE);
                        else          kb[o + (long)r * D_] = (bf16_t)v;
                    }
                }
            } else {
#pragma unroll
                for (int r = 0; r < 4; ++r)
                    outf[(long)(mbase + r) * 768 + n] = acc[i][j][r] + bv;
            }
        }
    }
}

// ---------- attention: QBLK=128 (4 waves x 32 q), KVBLK=128, sequential q-halves ----------
__global__ __launch_bounds__(256, 3)
void k_attn(const bf16_t* __restrict__ q, const bf16_t* __restrict__ k,
            const bf16_t* __restrict__ vt, bf16_t* __restrict__ ao) {
    __shared__ bf16_t Ks[128 * 64];    // [key][d], 128B rows, 3-bit chunk XOR
    __shared__ bf16_t Vs[64 * 128];    // [d][key], 256B rows, 4-bit chunk XOR
    __shared__ bf16_t Ps[4][16 * 128]; // per-wave [q][key], 256B rows, 4-bit chunk XOR
    int bid = blockIdx.x;
    int bh = bid >> 5, qt = bid & 31;
    int q0 = qt * 128;
    int b = bh / H_, h = bh % H_;
    int t = threadIdx.x, lane = t & 63, wid = t >> 6;
    int l15 = lane & 15, l4 = lane >> 4;

    const bf16_t* qp = q + (long)bh * S_ * D_;
    const bf16_t* kp = k + (long)bh * S_ * D_;
    const bf16_t* vp = vt + (long)bh * D_ * S_;
    int wqb = q0 + wid * 32;

    bf16x8 qf[2][2];
#pragma unroll
    for (int g = 0; g < 2; ++g) {
        int row = wqb + g * 16 + l15;
        qf[g][0] = *(const bf16x8*)(qp + (long)row * 64 + 8 * l4);
        qf[g][1] = *(const bf16x8*)(qp + (long)row * 64 + 32 + 8 * l4);
    }

    f32x4 o[2][4];
    float m[2][4], sum[2][4];
#pragma unroll
    for (int g = 0; g < 2; ++g)
#pragma unroll
        for (int ns = 0; ns < 4; ++ns) o[g][ns] = f32x4{0.f, 0.f, 0.f, 0.f};
#pragma unroll
    for (int g = 0; g < 2; ++g)
#pragma unroll
        for (int r = 0; r < 4; ++r) { m[g][r] = -1e30f; sum[g][r] = 0.f; }

    bf16_t* pw = &Ps[wid][0];

    for (int kt = 0; kt < 32; ++kt) {
        int k0 = kt << 7;
        if (k0 == q0) continue;  // 128x128 diagonal tile fully banned (block-uniform)
        bool maskt = (k0 == q0 - 128) || (k0 == q0 + 128);

        __syncthreads();
#pragma unroll
        for (int c = 0; c < 4; ++c) {
            int idx = t + 256 * c;
            int krow = idx >> 3, kpart = idx & 7;
            gload_lds16(kp + (long)(k0 + krow) * 64 + 8 * (kpart ^ (krow & 7)),
                        (char*)Ks + idx * 16);
            int vrow = idx >> 4, vpart = idx & 15;
            gload_lds16(vp + (long)vrow * S_ + k0 + 8 * (vpart ^ (vrow & 15)),
                        (char*)Vs + idx * 16);
        }
        __syncthreads();

#pragma unroll
        for (int g = 0; g < 2; ++g) {
            // QK^T for this q-half
            f32x4 s[8];
#pragma unroll
            for (int ks = 0; ks < 8; ++ks) {
                s[ks] = f32x4{0.f, 0.f, 0.f, 0.f};
                int row = ks * 16 + l15;
#pragma unroll
                for (int kk = 0; kk < 2; ++kk) {
                    bf16x8 kf = *(const bf16x8*)((const char*)Ks + row * 128 +
                                                 ((16 * (kk * 4 + l4)) ^ ((row & 7) << 4)));
                    s[ks] = __builtin_amdgcn_mfma_f32_16x16x32_bf16(qf[g][kk], kf, s[ks], 0, 0, 0);
                }
            }

            if (maskt) {
                int iq = wqb + g * 16 + l4 * 4;
#pragma unroll
                for (int ks = 0; ks < 8; ++ks) {
                    int j = k0 + ks * 16 + l15;
#pragma unroll
                    for (int r = 0; r < 4; ++r) {
                        int dd = iq + r - j; int ad = dd < 0 ? -dd : dd;
                        if (ad <= WINDOW_) s[ks][r] = -1e30f;
                    }
                }
            }
            // per-lane local max over the 8 ks-fragments
            float lm[4];
#pragma unroll
            for (int r = 0; r < 4; ++r) {
                float a0 = fmaxf(fmaxf(s[0][r], s[1][r]), fmaxf(s[2][r], s[3][r]));
                float a1 = fmaxf(fmaxf(s[4][r], s[5][r]), fmaxf(s[6][r], s[7][r]));
                lm[r] = fmaxf(a0, a1);
            }
            int ex = (lm[0] > m[g][0] + THR) | (lm[1] > m[g][1] + THR) |
                     (lm[2] > m[g][2] + THR) | (lm[3] > m[g][3] + THR);
            if (__any(ex)) {   // rescale path: rare after first tile
#pragma unroll
                for (int r = 0; r < 4; ++r) {
                    float tmv = lm[r];
                    tmv = fmaxf(tmv, __shfl_xor(tmv, 1));
                    tmv = fmaxf(tmv, __shfl_xor(tmv, 2));
                    tmv = fmaxf(tmv, __shfl_xor(tmv, 4));
                    tmv = fmaxf(tmv, __shfl_xor(tmv, 8));
                    float mn = fmaxf(m[g][r], tmv);
                    float f = exp2f(m[g][r] - mn);
                    m[g][r] = mn;
                    sum[g][r] *= f;
                    o[g][0][r] *= f; o[g][1][r] *= f; o[g][2][r] *= f; o[g][3][r] *= f;
                }
            }
            float ls[4] = {0.f, 0.f, 0.f, 0.f};
#pragma unroll
            for (int ks = 0; ks < 8; ++ks)
#pragma unroll
                for (int r = 0; r < 4; ++r) {
                    float p = exp2f(s[ks][r] - m[g][r]);
                    s[ks][r] = p;
                    ls[r] += p;
                }
#pragma unroll
            for (int r = 0; r < 4; ++r) {
                float v = ls[r];
                v += __shfl_xor(v, 1); v += __shfl_xor(v, 2);
                v += __shfl_xor(v, 4); v += __shfl_xor(v, 8);
                sum[g][r] += v;
            }
            // P -> LDS (wave-private, 4-bit chunk XOR on 256B rows)
#pragma unroll
            for (int ks = 0; ks < 8; ++ks)
#pragma unroll
                for (int r = 0; r < 4; ++r) {
                    int qr = l4 * 4 + r;
                    int byteoff = qr * 256 + ((2 * (ks * 16 + l15)) ^ ((qr & 15) << 4));
                    *(bf16_t*)((char*)pw + byteoff) = (bf16_t)s[ks][r];
                }
            asm volatile("s_waitcnt lgkmcnt(0)" ::: "memory");
            __builtin_amdgcn_sched_barrier(0);
            // PV
            bf16x8 pf[4];
#pragma unroll
            for (int kk = 0; kk < 4; ++kk)
                pf[kk] = *(const bf16x8*)((const char*)pw + l15 * 256 +
                                          ((16 * (kk * 4 + l4)) ^ ((l15 & 15) << 4)));
#pragma unroll
            for (int ns = 0; ns < 4; ++ns) {
                int drow = ns * 16 + l15;
#pragma unroll
                for (int kk = 0; kk < 4; ++kk) {
                    bf16x8 vf = *(const bf16x8*)((const char*)Vs + drow * 256 +
                                                 ((16 * (kk * 4 + l4)) ^ ((drow & 15) << 4)));
                    o[g][ns] = __builtin_amdgcn_mfma_f32_16x16x32_bf16(pf[kk], vf, o[g][ns], 0, 0, 0);
                }
            }
        }
    }

    // finalize + write [B,S,E] bf16
#pragma unroll
    for (int g = 0; g < 2; ++g) {
        float inv[4];
#pragma unroll
        for (int r = 0; r < 4; ++r) inv[r] = 1.0f / sum[g][r];
#pragma unroll
        for (int ns = 0; ns < 4; ++ns)
#pragma unroll
            for (int r = 0; r < 4; ++r) {
                int srow = wqb + g * 16 + l4 * 4 + r;
                int e = h * 64 + ns * 16 + l15;
                ao[((long)b * S_ + srow) * E_ + e] = (bf16_t)(o[g][ns][r] * inv[r]);
            }
    }
}

extern "C" void kernel_launch(void* const* d_in, const int* in_sizes, int n_in,
                              void* d_out, int out_size, void* d_ws, size_t ws_size,
                              hipStream_t stream) {
    const float* x     = (const float*)d_in[0];
    const float* w_in  = (const float*)d_in[1];
    const float* b_in  = (const float*)d_in[2];
    const float* w_out = (const float*)d_in[3];
    const float* b_out = (const float*)d_in[4];
    float* out = (float*)d_out;

    char* ws = (char*)d_ws;
    bf16_t* xb  = (bf16_t*)(ws + 0);          // 12582912 (reused as attn-out)
    bf16_t* wib = (bf16_t*)(ws + 12582912);   // 3538944
    bf16_t* wob = (bf16_t*)(ws + 16121856);   // 1179648
    bf16_t* qb  = (bf16_t*)(ws + 17301504);   // 12582912
    bf16_t* kb  = (bf16_t*)(ws + 29884416);   // 12582912
    bf16_t* vtb = (bf16_t*)(ws + 42467328);   // 12582912
    bf16_t* ao  = xb;

    k_cvt<<<6144, 256, 0, stream>>>(x, xb, 6291456);
    k_cvt<<<1728, 256, 0, stream>>>(w_in, wib, 1769472);
    k_cvt<<<576, 256, 0, stream>>>(w_out, wob, 589824);

    // QKV projection: M=8192, N=2304, K=768 (v written pre-transposed)
    k_gemm<0><<<64 * 18, 256, 0, stream>>>(xb, wib, b_in, qb, kb, vtb, nullptr,
                                           8192, 2304, 768, 64);
    k_attn<<<24 * 32, 256, 0, stream>>>(qb, kb, vtb, ao);
    // out projection: M=8192, N=768, K=768
    k_gemm<1><<<64 * 6, 256, 0, stream>>>(ao, wob, b_out, nullptr, nullptr, nullptr, out,
                                          8192, 768, 768, 64);
}

// Round 4
// 331.177 us; speedup vs baseline: 1.8220x; 1.1729x over previous
//
#include <hip/hip_runtime.h>
#include <hip/hip_bf16.h>
#include <stdint.h>

typedef __bf16 bf16_t;
typedef __bf16 bf16x8 __attribute__((ext_vector_type(8)));
typedef __bf16 bf16x4v __attribute__((ext_vector_type(4)));
typedef float f32x4 __attribute__((ext_vector_type(4)));

#define DEV __device__ __forceinline__

static constexpr int B_ = 2, S_ = 4096, E_ = 768, H_ = 12, D_ = 64;
static constexpr int WINDOW_ = 128;
static constexpr float QSCALE = 0.125f * 1.44269504088896f;  // fold log2(e): softmax via exp2
static constexpr float THR = 11.5f;                          // defer-max threshold (log2 domain)

// ---------- async 16B global -> LDS ----------
DEV void gload_lds16(const void* g, void* l) {
    __builtin_amdgcn_global_load_lds(
        (const __attribute__((address_space(1))) uint32_t*)g,
        (__attribute__((address_space(3))) uint32_t*)l, 16, 0, 0);
}

// ---------- fp32 -> bf16 convert ----------
__global__ void k_cvt(const float* __restrict__ in, bf16_t* __restrict__ out, int n) {
    int i = (blockIdx.x * blockDim.x + threadIdx.x) * 4;
    if (i < n) {
        float4 v = *(const float4*)(in + i);
        bf16x4v o;
        o[0] = (bf16_t)v.x; o[1] = (bf16_t)v.y; o[2] = (bf16_t)v.z; o[3] = (bf16_t)v.w;
        *(bf16x4v*)(out + i) = o;
    }
}

// ---------- NT GEMM: C[m][n] = sum_k A[m][k] * Bw[n][k] + bias[n] ----------
template<int EPI>
__global__ void k_gemm(const bf16_t* __restrict__ A, const bf16_t* __restrict__ Bw,
                       const float* __restrict__ bias,
                       bf16_t* __restrict__ qb, bf16_t* __restrict__ kb, bf16_t* __restrict__ vtb,
                       float* __restrict__ outf,
                       int M, int N, int K, int mtiles) {
    __shared__ bf16_t As[128 * 64];
    __shared__ bf16_t Bs[128 * 64];
    int bid = blockIdx.x;
    int tm = bid % mtiles, tn = bid / mtiles;
    int m0 = tm * 128, n0 = tn * 128;
    int t = threadIdx.x;
    int lane = t & 63, wid = t >> 6;
    int l15 = lane & 15, l4 = lane >> 4;
    int wm = (wid & 1) * 64, wn = (wid >> 1) * 64;

    f32x4 acc[4][4];
#pragma unroll
    for (int i = 0; i < 4; ++i)
#pragma unroll
        for (int j = 0; j < 4; ++j) acc[i][j] = f32x4{0.f, 0.f, 0.f, 0.f};

    for (int kt = 0; kt < K; kt += 64) {
        __syncthreads();
#pragma unroll
        for (int c = 0; c < 4; ++c) {
            int idx = t + 256 * c;
            int row = idx >> 3, part = idx & 7;
            int kc = 8 * (part ^ (row & 7));
            gload_lds16(A + (long)(m0 + row) * K + kt + kc, (char*)As + idx * 16);
            gload_lds16(Bw + (long)(n0 + row) * K + kt + kc, (char*)Bs + idx * 16);
        }
        __syncthreads();
#pragma unroll
        for (int kk = 0; kk < 2; ++kk) {
            bf16x8 af[4], bfr[4];
#pragma unroll
            for (int i = 0; i < 4; ++i) {
                int row = wm + i * 16 + l15;
                int off = row * 128 + ((16 * (kk * 4 + l4)) ^ ((row & 7) << 4));
                af[i] = *(const bf16x8*)((const char*)As + off);
                int rowb = wn + i * 16 + l15;
                int offb = rowb * 128 + ((16 * (kk * 4 + l4)) ^ ((rowb & 7) << 4));
                bfr[i] = *(const bf16x8*)((const char*)Bs + offb);
            }
#pragma unroll
            for (int i = 0; i < 4; ++i)
#pragma unroll
                for (int j = 0; j < 4; ++j)
                    acc[i][j] = __builtin_amdgcn_mfma_f32_16x16x32_bf16(af[i], bfr[j], acc[i][j], 0, 0, 0);
        }
    }

#pragma unroll
    for (int i = 0; i < 4; ++i) {
#pragma unroll
        for (int j = 0; j < 4; ++j) {
            int n = n0 + wn + j * 16 + l15;
            float bv = bias[n];
            int mbase = m0 + wm + i * 16 + l4 * 4;
            if (EPI == 0) {
                int sel = n / 768, nn = n % 768;
                int h = nn >> 6, d = nn & 63;
                int b = mbase >> 12, s = mbase & 4095;
                if (sel == 2) {
                    bf16x4v pk;
#pragma unroll
                    for (int r = 0; r < 4; ++r) pk[r] = (bf16_t)(acc[i][j][r] + bv);
                    *(bf16x4v*)(vtb + ((long)(b * H_ + h) * D_ + d) * S_ + s) = pk;
                } else {
                    long o = ((long)(b * H_ + h) * S_ + s) * D_ + d;
#pragma unroll
                    for (int r = 0; r < 4; ++r) {
                        float v = acc[i][j][r] + bv;
                        if (sel == 0) qb[o + (long)r * D_] = (bf16_t)(v * QSCALE);
                        else          kb[o + (long)r * D_] = (bf16_t)v;
                    }
                }
            } else {
#pragma unroll
                for (int r = 0; r < 4; ++r)
                    outf[(long)(mbase + r) * 768 + n] = acc[i][j][r] + bv;
            }
        }
    }
}

// ---------- attention: swapped QK^T, lane-local softmax, in-register P ----------
// QBLK=128 (4 waves x 32 q), KVBLK=128, double-buffered K/V staging.
__global__ __launch_bounds__(256, 2)
void k_attn(const bf16_t* __restrict__ q, const bf16_t* __restrict__ k,
            const bf16_t* __restrict__ vt, bf16_t* __restrict__ ao) {
    __shared__ bf16_t Ksh[2][128 * 64];   // [key][d], 128B rows, 3-bit chunk XOR
    __shared__ bf16_t Vsh[2][64 * 128];   // [d][key], 256B rows, 4-bit chunk XOR
    int bid = blockIdx.x;
    bid = (bid & 7) * 96 + (bid >> 3);    // XCD-aware swizzle (768 = 8*96)
    int bh = bid >> 5, qt = bid & 31;
    int q0 = qt * 128;
    int b = bh / H_, h = bh % H_;
    int t = threadIdx.x, lane = t & 63, wid = t >> 6;
    int l15 = lane & 15, l4 = lane >> 4;

    const bf16_t* qp = q + (long)bh * S_ * D_;
    const bf16_t* kp = k + (long)bh * S_ * D_;
    const bf16_t* vp = vt + (long)bh * D_ * S_;
    int wqb = q0 + wid * 32;

    // Q fragments (B-operand: col=q=l15, contraction d-chunk 8*l4)
    bf16x8 qf[2][2];
#pragma unroll
    for (int g = 0; g < 2; ++g) {
        int row = wqb + g * 16 + l15;
        qf[g][0] = *(const bf16x8*)(qp + (long)row * 64 + 8 * l4);
        qf[g][1] = *(const bf16x8*)(qp + (long)row * 64 + 32 + 8 * l4);
    }

    f32x4 o[2][4];
#pragma unroll
    for (int g = 0; g < 2; ++g)
#pragma unroll
        for (int ns = 0; ns < 4; ++ns) o[g][ns] = f32x4{0.f, 0.f, 0.f, 0.f};
    float m[2] = {-1e30f, -1e30f};
    float sum[2] = {0.f, 0.f};

    auto STAGE = [&](int tidx, int buf) {
        int kts = tidx < qt ? tidx : tidx + 1;
        int k0s = kts << 7;
        char* Kd = (char*)Ksh[buf];
        char* Vd = (char*)Vsh[buf];
#pragma unroll
        for (int c = 0; c < 4; ++c) {
            int idx2 = t + 256 * c;
            int krow = idx2 >> 3, kpart = idx2 & 7;
            gload_lds16(kp + (long)(k0s + krow) * 64 + 8 * (kpart ^ (krow & 7)), Kd + idx2 * 16);
            int vrow = idx2 >> 4, vpart = idx2 & 15;
            gload_lds16(vp + (long)vrow * S_ + k0s + 8 * (vpart ^ (vrow & 15)), Vd + idx2 * 16);
        }
    };

    STAGE(0, 0);
    asm volatile("s_waitcnt vmcnt(0)" ::: "memory");  // drain qf + tile0 (one-time)

    for (int idx = 0; idx < 31; ++idx) {
        int cur = idx & 1;
        if (idx + 1 < 31) {
            STAGE(idx + 1, cur ^ 1);
            asm volatile("s_waitcnt vmcnt(8)" ::: "memory");  // tile idx landed; next in flight
        } else {
            asm volatile("s_waitcnt vmcnt(0)" ::: "memory");
        }
        __builtin_amdgcn_s_barrier();
        __builtin_amdgcn_sched_barrier(0);

        int kt = idx < qt ? idx : idx + 1;
        int k0 = kt << 7;
        bool maskt = (kt == qt - 1) || (kt == qt + 1);
        const char* Kb = (const char*)Ksh[cur];
        const char* Vb = (const char*)Vsh[cur];

        // QK^T swapped: S'[key=(l4*4+r)+16ks][q=l15]; K fragments shared across g
        f32x4 s0[8], s1[8];
#pragma unroll
        for (int ks = 0; ks < 8; ++ks) { s0[ks] = f32x4{0,0,0,0}; s1[ks] = f32x4{0,0,0,0}; }
#pragma unroll
        for (int ks = 0; ks < 8; ++ks) {
            int row = ks * 16 + l15;
            const char* kro = Kb + row * 128;
            int sw = (row & 7) << 4;
#pragma unroll
            for (int kk = 0; kk < 2; ++kk) {
                bf16x8 kf = *(const bf16x8*)(kro + ((16 * (kk * 4 + l4)) ^ sw));
                s0[ks] = __builtin_amdgcn_mfma_f32_16x16x32_bf16(kf, qf[0][kk], s0[ks], 0, 0, 0);
                s1[ks] = __builtin_amdgcn_mfma_f32_16x16x32_bf16(kf, qf[1][kk], s1[ks], 0, 0, 0);
            }
        }

#pragma unroll
        for (int g = 0; g < 2; ++g) {
            f32x4* sg = g ? s1 : s0;
            if (maskt) {
                int qg = wqb + g * 16 + l15;
#pragma unroll
                for (int ks = 0; ks < 8; ++ks) {
                    int kb_ = k0 + ks * 16 + l4 * 4;
#pragma unroll
                    for (int r = 0; r < 4; ++r) {
                        int dd = qg - (kb_ + r); int ad = dd < 0 ? -dd : dd;
                        if (ad <= WINDOW_) sg[ks][r] = -1e30f;
                    }
                }
            }
            // lane-local row max (q = l15), reduce across l4 groups
            float lm = -1e30f;
#pragma unroll
            for (int ks = 0; ks < 8; ++ks) {
                float a = fmaxf(fmaxf(sg[ks][0], sg[ks][1]), fmaxf(sg[ks][2], sg[ks][3]));
                lm = fmaxf(lm, a);
            }
            lm = fmaxf(lm, __shfl_xor(lm, 16));
            lm = fmaxf(lm, __shfl_xor(lm, 32));
            if (__any(lm > m[g] + THR)) {   // rare after first tile
                float mn = fmaxf(m[g], lm);
                float f = exp2f(m[g] - mn);
                m[g] = mn; sum[g] *= f;
#pragma unroll
                for (int r = 0; r < 4; ++r) {
                    float fr = __shfl(f, l4 * 4 + r);
#pragma unroll
                    for (int ns = 0; ns < 4; ++ns) o[g][ns][r] *= fr;
                }
            }
            float ls = 0.f;
#pragma unroll
            for (int ks = 0; ks < 8; ++ks)
#pragma unroll
                for (int r = 0; r < 4; ++r) {
                    float p = exp2f(sg[ks][r] - m[g]);
                    sg[ks][r] = p;
                    ls += p;
                }
            ls += __shfl_xor(ls, 16);
            ls += __shfl_xor(ls, 32);
            sum[g] += ls;

            // pack P into permuted-slot A-fragments (lane-local, no LDS transit):
            // slot 8*l4+{0..3} <- keys 32c+4*l4+{0..3}, slot 8*l4+{4..7} <- keys 32c+16+4*l4+{0..3}
            bf16x8 pa[4];
#pragma unroll
            for (int c = 0; c < 4; ++c) {
                pa[c][0] = (bf16_t)sg[2*c][0];   pa[c][1] = (bf16_t)sg[2*c][1];
                pa[c][2] = (bf16_t)sg[2*c][2];   pa[c][3] = (bf16_t)sg[2*c][3];
                pa[c][4] = (bf16_t)sg[2*c+1][0]; pa[c][5] = (bf16_t)sg[2*c+1][1];
                pa[c][6] = (bf16_t)sg[2*c+1][2]; pa[c][7] = (bf16_t)sg[2*c+1][3];
            }
            // PV: B-fragment rows permuted to match (keys 32c+4*l4, 32c+16+4*l4)
#pragma unroll
            for (int ns = 0; ns < 4; ++ns) {
                int drow = ns * 16 + l15;
                const char* vro = Vb + drow * 256;
                int sw = (drow & 15) << 4;
#pragma unroll
                for (int c = 0; c < 4; ++c) {
                    bf16x4v v0 = *(const bf16x4v*)(vro + ((64 * c + 8 * l4) ^ sw));
                    bf16x4v v1 = *(const bf16x4v*)(vro + ((64 * c + 32 + 8 * l4) ^ sw));
                    bf16x8 vf = {v0[0], v0[1], v0[2], v0[3], v1[0], v1[1], v1[2], v1[3]};
                    o[g][ns] = __builtin_amdgcn_mfma_f32_16x16x32_bf16(pa[c], vf, o[g][ns], 0, 0, 0);
                }
            }
        }
        __builtin_amdgcn_sched_barrier(0);
        __builtin_amdgcn_s_barrier();
    }

    // finalize + write [B,S,E] bf16 (sum lives at lane l15=q; broadcast to o-rows)
#pragma unroll
    for (int g = 0; g < 2; ++g) {
        float inv = 1.0f / sum[g];
#pragma unroll
        for (int r = 0; r < 4; ++r) {
            float ir = __shfl(inv, l4 * 4 + r);
            int srow = wqb + g * 16 + l4 * 4 + r;
#pragma unroll
            for (int ns = 0; ns < 4; ++ns) {
                int e = h * 64 + ns * 16 + l15;
                ao[((long)b * S_ + srow) * E_ + e] = (bf16_t)(o[g][ns][r] * ir);
            }
        }
    }
}

extern "C" void kernel_launch(void* const* d_in, const int* in_sizes, int n_in,
                              void* d_out, int out_size, void* d_ws, size_t ws_size,
                              hipStream_t stream) {
    const float* x     = (const float*)d_in[0];
    const float* w_in  = (const float*)d_in[1];
    const float* b_in  = (const float*)d_in[2];
    const float* w_out = (const float*)d_in[3];
    const float* b_out = (const float*)d_in[4];
    float* out = (float*)d_out;

    char* ws = (char*)d_ws;
    bf16_t* xb  = (bf16_t*)(ws + 0);          // 12582912 (reused as attn-out)
    bf16_t* wib = (bf16_t*)(ws + 12582912);   // 3538944
    bf16_t* wob = (bf16_t*)(ws + 16121856);   // 1179648
    bf16_t* qb  = (bf16_t*)(ws + 17301504);   // 12582912
    bf16_t* kb  = (bf16_t*)(ws + 29884416);   // 12582912
    bf16_t* vtb = (bf16_t*)(ws + 42467328);   // 12582912
    bf16_t* ao  = xb;

    k_cvt<<<6144, 256, 0, stream>>>(x, xb, 6291456);
    k_cvt<<<1728, 256, 0, stream>>>(w_in, wib, 1769472);
    k_cvt<<<576, 256, 0, stream>>>(w_out, wob, 589824);

    // QKV projection: M=8192, N=2304, K=768 (v written pre-transposed)
    k_gemm<0><<<64 * 18, 256, 0, stream>>>(xb, wib, b_in, qb, kb, vtb, nullptr,
                                           8192, 2304, 768, 64);
    k_attn<<<24 * 32, 256, 0, stream>>>(qb, kb, vtb, ao);
    // out projection: M=8192, N=768, K=768
    k_gemm<1><<<64 * 6, 256, 0, stream>>>(ao, wob, b_out, nullptr, nullptr, nullptr, out,
                                          8192, 768, 768, 64);
}

// Round 5
// 330.375 us; speedup vs baseline: 1.8264x; 1.0024x over previous
//
#include <hip/hip_runtime.h>
#include <hip/hip_bf16.h>
#include <stdint.h>

typedef __bf16 bf16_t;
typedef __bf16 bf16x8 __attribute__((ext_vector_type(8)));
typedef __bf16 bf16x4v __attribute__((ext_vector_type(4)));
typedef float f32x4 __attribute__((ext_vector_type(4)));

#define DEV __device__ __forceinline__

static constexpr int B_ = 2, S_ = 4096, E_ = 768, H_ = 12, D_ = 64;
static constexpr int WINDOW_ = 128;
static constexpr float QSCALE = 0.125f * 1.44269504088896f;  // fold log2(e): softmax via exp2
static constexpr float THR = 11.5f;                          // defer-max threshold (log2 domain)

// ---------- async 16B global -> LDS ----------
DEV void gload_lds16(const void* g, void* l) {
    __builtin_amdgcn_global_load_lds(
        (const __attribute__((address_space(1))) uint32_t*)g,
        (__attribute__((address_space(3))) uint32_t*)l, 16, 0, 0);
}

// ---------- fp32 -> bf16 convert ----------
__global__ void k_cvt(const float* __restrict__ in, bf16_t* __restrict__ out, int n) {
    int i = (blockIdx.x * blockDim.x + threadIdx.x) * 4;
    if (i < n) {
        float4 v = *(const float4*)(in + i);
        bf16x4v o;
        o[0] = (bf16_t)v.x; o[1] = (bf16_t)v.y; o[2] = (bf16_t)v.z; o[3] = (bf16_t)v.w;
        *(bf16x4v*)(out + i) = o;
    }
}

// ---------- NT GEMM: C[m][n] = sum_k A[m][k] * Bw[n][k] + bias[n] ----------
template<int EPI>
__global__ void k_gemm(const bf16_t* __restrict__ A, const bf16_t* __restrict__ Bw,
                       const float* __restrict__ bias,
                       bf16_t* __restrict__ qb, bf16_t* __restrict__ kb, bf16_t* __restrict__ vtb,
                       float* __restrict__ outf,
                       int M, int N, int K, int mtiles) {
    __shared__ bf16_t As[128 * 64];
    __shared__ bf16_t Bs[128 * 64];
    int bid = blockIdx.x;
    int tm = bid % mtiles, tn = bid / mtiles;
    int m0 = tm * 128, n0 = tn * 128;
    int t = threadIdx.x;
    int lane = t & 63, wid = t >> 6;
    int l15 = lane & 15, l4 = lane >> 4;
    int wm = (wid & 1) * 64, wn = (wid >> 1) * 64;

    f32x4 acc[4][4];
#pragma unroll
    for (int i = 0; i < 4; ++i)
#pragma unroll
        for (int j = 0; j < 4; ++j) acc[i][j] = f32x4{0.f, 0.f, 0.f, 0.f};

    for (int kt = 0; kt < K; kt += 64) {
        __syncthreads();
#pragma unroll
        for (int c = 0; c < 4; ++c) {
            int idx = t + 256 * c;
            int row = idx >> 3, part = idx & 7;
            int kc = 8 * (part ^ (row & 7));
            gload_lds16(A + (long)(m0 + row) * K + kt + kc, (char*)As + idx * 16);
            gload_lds16(Bw + (long)(n0 + row) * K + kt + kc, (char*)Bs + idx * 16);
        }
        __syncthreads();
#pragma unroll
        for (int kk = 0; kk < 2; ++kk) {
            bf16x8 af[4], bfr[4];
#pragma unroll
            for (int i = 0; i < 4; ++i) {
                int row = wm + i * 16 + l15;
                int off = row * 128 + ((16 * (kk * 4 + l4)) ^ ((row & 7) << 4));
                af[i] = *(const bf16x8*)((const char*)As + off);
                int rowb = wn + i * 16 + l15;
                int offb = rowb * 128 + ((16 * (kk * 4 + l4)) ^ ((rowb & 7) << 4));
                bfr[i] = *(const bf16x8*)((const char*)Bs + offb);
            }
#pragma unroll
            for (int i = 0; i < 4; ++i)
#pragma unroll
                for (int j = 0; j < 4; ++j)
                    acc[i][j] = __builtin_amdgcn_mfma_f32_16x16x32_bf16(af[i], bfr[j], acc[i][j], 0, 0, 0);
        }
    }

#pragma unroll
    for (int i = 0; i < 4; ++i) {
#pragma unroll
        for (int j = 0; j < 4; ++j) {
            int n = n0 + wn + j * 16 + l15;
            float bv = bias[n];
            int mbase = m0 + wm + i * 16 + l4 * 4;
            if (EPI == 0) {
                int sel = n / 768, nn = n % 768;
                int h = nn >> 6, d = nn & 63;
                int b = mbase >> 12, s = mbase & 4095;
                if (sel == 2) {
                    bf16x4v pk;
#pragma unroll
                    for (int r = 0; r < 4; ++r) pk[r] = (bf16_t)(acc[i][j][r] + bv);
                    *(bf16x4v*)(vtb + ((long)(b * H_ + h) * D_ + d) * S_ + s) = pk;
                } else {
                    long o = ((long)(b * H_ + h) * S_ + s) * D_ + d;
#pragma unroll
                    for (int r = 0; r < 4; ++r) {
                        float v = acc[i][j][r] + bv;
                        if (sel == 0) qb[o + (long)r * D_] = (bf16_t)(v * QSCALE);
                        else          kb[o + (long)r * D_] = (bf16_t)v;
                    }
                }
            } else {
#pragma unroll
                for (int r = 0; r < 4; ++r)
                    outf[(long)(mbase + r) * 768 + n] = acc[i][j][r] + bv;
            }
        }
    }
}

// ---------- attention: swapped QK^T, lane-local softmax, in-register P ----------
// QBLK=128 (4 waves x 32 q), KVBLK=128, double-buffered K/V staging.
__global__ __launch_bounds__(256, 2)
void k_attn(const bf16_t* __restrict__ q, const bf16_t* __restrict__ k,
            const bf16_t* __restrict__ vt, bf16_t* __restrict__ ao) {
    __shared__ bf16_t Ksh[2][128 * 64];   // [key][d], 128B rows, 3-bit chunk XOR
    __shared__ bf16_t Vsh[2][64 * 128];   // [d][key], 256B rows, 4-bit chunk XOR
    int bid = blockIdx.x;
    bid = (bid & 7) * 96 + (bid >> 3);    // XCD-aware swizzle (768 = 8*96)
    int bh = bid >> 5, qt = bid & 31;
    int q0 = qt * 128;
    int b = bh / H_, h = bh % H_;
    int t = threadIdx.x, lane = t & 63, wid = t >> 6;
    int l15 = lane & 15, l4 = lane >> 4;

    const bf16_t* qp = q + (long)bh * S_ * D_;
    const bf16_t* kp = k + (long)bh * S_ * D_;
    const bf16_t* vp = vt + (long)bh * D_ * S_;
    int wqb = q0 + wid * 32;

    // Q fragments (B-operand: col=q=l15, contraction d-chunk 8*l4)
    bf16x8 qf[2][2];
#pragma unroll
    for (int g = 0; g < 2; ++g) {
        int row = wqb + g * 16 + l15;
        qf[g][0] = *(const bf16x8*)(qp + (long)row * 64 + 8 * l4);
        qf[g][1] = *(const bf16x8*)(qp + (long)row * 64 + 32 + 8 * l4);
    }

    f32x4 o[2][4];
#pragma unroll
    for (int g = 0; g < 2; ++g)
#pragma unroll
        for (int ns = 0; ns < 4; ++ns) o[g][ns] = f32x4{0.f, 0.f, 0.f, 0.f};
    float m[2] = {-1e30f, -1e30f};
    float sum[2] = {0.f, 0.f};

    auto STAGE = [&](int tidx, int buf) {
        int kts = tidx < qt ? tidx : tidx + 1;
        int k0s = kts << 7;
        char* Kd = (char*)Ksh[buf];
        char* Vd = (char*)Vsh[buf];
#pragma unroll
        for (int c = 0; c < 4; ++c) {
            int idx2 = t + 256 * c;
            int krow = idx2 >> 3, kpart = idx2 & 7;
            gload_lds16(kp + (long)(k0s + krow) * 64 + 8 * (kpart ^ (krow & 7)), Kd + idx2 * 16);
            int vrow = idx2 >> 4, vpart = idx2 & 15;
            gload_lds16(vp + (long)vrow * S_ + k0s + 8 * (vpart ^ (vrow & 15)), Vd + idx2 * 16);
        }
    };

    STAGE(0, 0);
    asm volatile("s_waitcnt vmcnt(0)" ::: "memory");  // drain qf + tile0 (one-time)

    for (int idx = 0; idx < 31; ++idx) {
        int cur = idx & 1;
        if (idx + 1 < 31) {
            STAGE(idx + 1, cur ^ 1);
            asm volatile("s_waitcnt vmcnt(8)" ::: "memory");  // tile idx landed; next in flight
        } else {
            asm volatile("s_waitcnt vmcnt(0)" ::: "memory");
        }
        __builtin_amdgcn_s_barrier();
        __builtin_amdgcn_sched_barrier(0);

        int kt = idx < qt ? idx : idx + 1;
        int k0 = kt << 7;
        bool maskt = (kt == qt - 1) || (kt == qt + 1);
        const char* Kb = (const char*)Ksh[cur];
        const char* Vb = (const char*)Vsh[cur];

        // QK^T swapped: S'[key=(l4*4+r)+16ks][q=l15]; K fragments shared across g
        f32x4 s0[8], s1[8];
#pragma unroll
        for (int ks = 0; ks < 8; ++ks) { s0[ks] = f32x4{0,0,0,0}; s1[ks] = f32x4{0,0,0,0}; }
#pragma unroll
        for (int ks = 0; ks < 8; ++ks) {
            int row = ks * 16 + l15;
            const char* kro = Kb + row * 128;
            int sw = (row & 7) << 4;
#pragma unroll
            for (int kk = 0; kk < 2; ++kk) {
                bf16x8 kf = *(const bf16x8*)(kro + ((16 * (kk * 4 + l4)) ^ sw));
                s0[ks] = __builtin_amdgcn_mfma_f32_16x16x32_bf16(kf, qf[0][kk], s0[ks], 0, 0, 0);
                s1[ks] = __builtin_amdgcn_mfma_f32_16x16x32_bf16(kf, qf[1][kk], s1[ks], 0, 0, 0);
            }
        }

#pragma unroll
        for (int g = 0; g < 2; ++g) {
            f32x4* sg = g ? s1 : s0;
            if (maskt) {
                int qg = wqb + g * 16 + l15;
#pragma unroll
                for (int ks = 0; ks < 8; ++ks) {
                    int kb_ = k0 + ks * 16 + l4 * 4;
#pragma unroll
                    for (int r = 0; r < 4; ++r) {
                        int dd = qg - (kb_ + r); int ad = dd < 0 ? -dd : dd;
                        if (ad <= WINDOW_) sg[ks][r] = -1e30f;
                    }
                }
            }
            // lane-local row max (q = l15), reduce across l4 groups
            float lm = -1e30f;
#pragma unroll
            for (int ks = 0; ks < 8; ++ks) {
                float a = fmaxf(fmaxf(sg[ks][0], sg[ks][1]), fmaxf(sg[ks][2], sg[ks][3]));
                lm = fmaxf(lm, a);
            }
            lm = fmaxf(lm, __shfl_xor(lm, 16));
            lm = fmaxf(lm, __shfl_xor(lm, 32));
            if (__any(lm > m[g] + THR)) {   // rare after first tile
                float mn = fmaxf(m[g], lm);
                float f = exp2f(m[g] - mn);
                m[g] = mn; sum[g] *= f;
#pragma unroll
                for (int r = 0; r < 4; ++r) {
                    float fr = __shfl(f, l4 * 4 + r);
#pragma unroll
                    for (int ns = 0; ns < 4; ++ns) o[g][ns][r] *= fr;
                }
            }
            float ls = 0.f;
#pragma unroll
            for (int ks = 0; ks < 8; ++ks)
#pragma unroll
                for (int r = 0; r < 4; ++r) {
                    float p = exp2f(sg[ks][r] - m[g]);
                    sg[ks][r] = p;
                    ls += p;
                }
            ls += __shfl_xor(ls, 16);
            ls += __shfl_xor(ls, 32);
            sum[g] += ls;

            // pack P into permuted-slot A-fragments (lane-local, no LDS transit):
            // slot 8*l4+{0..3} <- keys 32c+4*l4+{0..3}, slot 8*l4+{4..7} <- keys 32c+16+4*l4+{0..3}
            bf16x8 pa[4];
#pragma unroll
            for (int c = 0; c < 4; ++c) {
                pa[c][0] = (bf16_t)sg[2*c][0];   pa[c][1] = (bf16_t)sg[2*c][1];
                pa[c][2] = (bf16_t)sg[2*c][2];   pa[c][3] = (bf16_t)sg[2*c][3];
                pa[c][4] = (bf16_t)sg[2*c+1][0]; pa[c][5] = (bf16_t)sg[2*c+1][1];
                pa[c][6] = (bf16_t)sg[2*c+1][2]; pa[c][7] = (bf16_t)sg[2*c+1][3];
            }
            // PV: B-fragment rows permuted to match (keys 32c+4*l4, 32c+16+4*l4)
#pragma unroll
            for (int ns = 0; ns < 4; ++ns) {
                int drow = ns * 16 + l15;
                const char* vro = Vb + drow * 256;
                int sw = (drow & 15) << 4;
#pragma unroll
                for (int c = 0; c < 4; ++c) {
                    bf16x4v v0 = *(const bf16x4v*)(vro + ((64 * c + 8 * l4) ^ sw));
                    bf16x4v v1 = *(const bf16x4v*)(vro + ((64 * c + 32 + 8 * l4) ^ sw));
                    bf16x8 vf = {v0[0], v0[1], v0[2], v0[3], v1[0], v1[1], v1[2], v1[3]};
                    o[g][ns] = __builtin_amdgcn_mfma_f32_16x16x32_bf16(pa[c], vf, o[g][ns], 0, 0, 0);
                }
            }
        }
        __builtin_amdgcn_sched_barrier(0);
        __builtin_amdgcn_s_barrier();
    }

    // finalize + write [B,S,E] bf16 (sum lives at lane l15=q; broadcast to o-rows)
#pragma unroll
    for (int g = 0; g < 2; ++g) {
        float inv = 1.0f / sum[g];
#pragma unroll
        for (int r = 0; r < 4; ++r) {
            float ir = __shfl(inv, l4 * 4 + r);
            int srow = wqb + g * 16 + l4 * 4 + r;
#pragma unroll
            for (int ns = 0; ns < 4; ++ns) {
                int e = h * 64 + ns * 16 + l15;
                ao[((long)b * S_ + srow) * E_ + e] = (bf16_t)(o[g][ns][r] * ir);
            }
        }
    }
}

extern "C" void kernel_launch(void* const* d_in, const int* in_sizes, int n_in,
                              void* d_out, int out_size, void* d_ws, size_t ws_size,
                              hipStream_t stream) {
    const float* x     = (const float*)d_in[0];
    const float* w_in  = (const float*)d_in[1];
    const float* b_in  = (const float*)d_in[2];
    const float* w_out = (const float*)d_in[3];
    const float* b_out = (const float*)d_in[4];
    float* out = (float*)d_out;

    char* ws = (char*)d_ws;
    bf16_t* xb  = (bf16_t*)(ws + 0);          // 12582912 (reused as attn-out)
    bf16_t* wib = (bf16_t*)(ws + 12582912);   // 3538944
    bf16_t* wob = (bf16_t*)(ws + 16121856);   // 1179648
    bf16_t* qb  = (bf16_t*)(ws + 17301504);   // 12582912
    bf16_t* kb  = (bf16_t*)(ws + 29884416);   // 12582912
    bf16_t* vtb = (bf16_t*)(ws + 42467328);   // 12582912
    bf16_t* ao  = xb;

    k_cvt<<<6144, 256, 0, stream>>>(x, xb, 6291456);
    k_cvt<<<1728, 256, 0, stream>>>(w_in, wib, 1769472);
    k_cvt<<<576, 256, 0, stream>>>(w_out, wob, 589824);

    // QKV projection: M=8192, N=2304, K=768 (v written pre-transposed)
    k_gemm<0><<<64 * 18, 256, 0, stream>>>(xb, wib, b_in, qb, kb, vtb, nullptr,
                                           8192, 2304, 768, 64);
    k_attn<<<24 * 32, 256, 0, stream>>>(qb, kb, vtb, ao);
    // out projection: M=8192, N=768, K=768
    k_gemm<1><<<64 * 6, 256, 0, stream>>>(ao, wob, b_out, nullptr, nullptr, nullptr, out,
                                          8192, 768, 768, 64);
}

// Round 6
// 304.894 us; speedup vs baseline: 1.9791x; 1.0836x over previous
//
#include <hip/hip_runtime.h>
#include <hip/hip_bf16.h>
#include <stdint.h>

typedef __bf16 bf16_t;
typedef __bf16 bf16x8 __attribute__((ext_vector_type(8)));
typedef __bf16 bf16x4v __attribute__((ext_vector_type(4)));
typedef float f32x4 __attribute__((ext_vector_type(4)));

#define DEV __device__ __forceinline__

static constexpr int B_ = 2, S_ = 4096, E_ = 768, H_ = 12, D_ = 64;
static constexpr int WINDOW_ = 128;
static constexpr float QSCALE = 0.125f * 1.44269504088896f;  // fold log2(e): softmax via exp2
static constexpr float THR = 11.5f;                          // defer-max threshold (log2 domain)

// ---------- async 16B global -> LDS ----------
DEV void gload_lds16(const void* g, void* l) {
    __builtin_amdgcn_global_load_lds(
        (const __attribute__((address_space(1))) uint32_t*)g,
        (__attribute__((address_space(3))) uint32_t*)l, 16, 0, 0);
}

// ---------- fp32 -> bf16 convert ----------
__global__ void k_cvt(const float* __restrict__ in, bf16_t* __restrict__ out, int n) {
    int i = (blockIdx.x * blockDim.x + threadIdx.x) * 4;
    if (i < n) {
        float4 v = *(const float4*)(in + i);
        bf16x4v o;
        o[0] = (bf16_t)v.x; o[1] = (bf16_t)v.y; o[2] = (bf16_t)v.z; o[3] = (bf16_t)v.w;
        *(bf16x4v*)(out + i) = o;
    }
}

// ---------- NT GEMM: C[m][n] = sum_k A[m][k] * Bw[n][k] + bias[n] ----------
// EPI 0: q (scaled, exp2-domain) / k into [B,H,S,D]; v into vt [B,H,D,S] with keys
//        pre-permuted within 32-groups to match the PV A-fragment slot order.
// EPI 1: fp32 output [M][N]
template<int EPI>
__global__ void k_gemm(const bf16_t* __restrict__ A, const bf16_t* __restrict__ Bw,
                       const float* __restrict__ bias,
                       bf16_t* __restrict__ qb, bf16_t* __restrict__ kb, bf16_t* __restrict__ vtb,
                       float* __restrict__ outf,
                       int M, int N, int K, int mtiles) {
    __shared__ bf16_t As[128 * 64];
    __shared__ bf16_t Bs[128 * 64];
    int bid = blockIdx.x;
    int tm = bid % mtiles, tn = bid / mtiles;
    int m0 = tm * 128, n0 = tn * 128;
    int t = threadIdx.x;
    int lane = t & 63, wid = t >> 6;
    int l15 = lane & 15, l4 = lane >> 4;
    int wm = (wid & 1) * 64, wn = (wid >> 1) * 64;

    f32x4 acc[4][4];
#pragma unroll
    for (int i = 0; i < 4; ++i)
#pragma unroll
        for (int j = 0; j < 4; ++j) acc[i][j] = f32x4{0.f, 0.f, 0.f, 0.f};

    for (int kt = 0; kt < K; kt += 64) {
        __syncthreads();
#pragma unroll
        for (int c = 0; c < 4; ++c) {
            int idx = t + 256 * c;
            int row = idx >> 3, part = idx & 7;
            int kc = 8 * (part ^ (row & 7));
            gload_lds16(A + (long)(m0 + row) * K + kt + kc, (char*)As + idx * 16);
            gload_lds16(Bw + (long)(n0 + row) * K + kt + kc, (char*)Bs + idx * 16);
        }
        __syncthreads();
#pragma unroll
        for (int kk = 0; kk < 2; ++kk) {
            bf16x8 af[4], bfr[4];
#pragma unroll
            for (int i = 0; i < 4; ++i) {
                int row = wm + i * 16 + l15;
                int off = row * 128 + ((16 * (kk * 4 + l4)) ^ ((row & 7) << 4));
                af[i] = *(const bf16x8*)((const char*)As + off);
                int rowb = wn + i * 16 + l15;
                int offb = rowb * 128 + ((16 * (kk * 4 + l4)) ^ ((rowb & 7) << 4));
                bfr[i] = *(const bf16x8*)((const char*)Bs + offb);
            }
#pragma unroll
            for (int i = 0; i < 4; ++i)
#pragma unroll
                for (int j = 0; j < 4; ++j)
                    acc[i][j] = __builtin_amdgcn_mfma_f32_16x16x32_bf16(af[i], bfr[j], acc[i][j], 0, 0, 0);
        }
    }

#pragma unroll
    for (int i = 0; i < 4; ++i) {
#pragma unroll
        for (int j = 0; j < 4; ++j) {
            int n = n0 + wn + j * 16 + l15;
            float bv = bias[n];
            int mbase = m0 + wm + i * 16 + l4 * 4;
            if (EPI == 0) {
                int sel = n / 768, nn = n % 768;
                int h = nn >> 6, d = nn & 63;
                int b = mbase >> 12, s = mbase & 4095;
                if (sel == 2) {
                    bf16x4v pk;
#pragma unroll
                    for (int r = 0; r < 4; ++r) pk[r] = (bf16_t)(acc[i][j][r] + bv);
                    // permuted position: slot(8a+j)<-key(4a+j), slot(8a+4+j)<-key(16+4a+j)
                    int pos = (s & ~31) | (((s >> 2) & 3) << 3) | (((s >> 4) & 1) << 2);
                    *(bf16x4v*)(vtb + ((long)(b * H_ + h) * D_ + d) * S_ + pos) = pk;
                } else {
                    long o = ((long)(b * H_ + h) * S_ + s) * D_ + d;
#pragma unroll
                    for (int r = 0; r < 4; ++r) {
                        float v = acc[i][j][r] + bv;
                        if (sel == 0) qb[o + (long)r * D_] = (bf16_t)(v * QSCALE);
                        else          kb[o + (long)r * D_] = (bf16_t)v;
                    }
                }
            } else {
#pragma unroll
                for (int r = 0; r < 4; ++r)
                    outf[(long)(mbase + r) * 768 + n] = acc[i][j][r] + bv;
            }
        }
    }
}

// ---------- attention: swapped QK^T, lane-local softmax, in-register P ----------
// QBLK=128 (4 waves x 32 q), KVBLK=64, double-buffered K/V, mfma row-sum.
__global__ __launch_bounds__(256, 4)
void k_attn(const bf16_t* __restrict__ q, const bf16_t* __restrict__ k,
            const bf16_t* __restrict__ vt, bf16_t* __restrict__ ao) {
    __shared__ bf16_t Ksh[2][64 * 64];   // [key][d], 128B rows, 3-bit chunk XOR
    __shared__ bf16_t Vsh[2][64 * 64];   // [d][pos], 128B rows, 3-bit chunk XOR
    int bid = blockIdx.x;
    bid = (bid & 7) * 96 + (bid >> 3);    // XCD-aware swizzle (768 = 8*96)
    int bh = bid >> 5, qt = bid & 31;
    int q0 = qt * 128;
    int b = bh / H_, h = bh % H_;
    int t = threadIdx.x, lane = t & 63, wid = t >> 6;
    int l15 = lane & 15, l4 = lane >> 4;

    const bf16_t* qp = q + (long)bh * S_ * D_;
    const bf16_t* kp = k + (long)bh * S_ * D_;
    const bf16_t* vp = vt + (long)bh * D_ * S_;
    int wqb = q0 + wid * 32;

    // Q fragments (B-operand: col=q=l15, contraction d-chunk 8*l4)
    bf16x8 qf[2][2];
#pragma unroll
    for (int g = 0; g < 2; ++g) {
        int row = wqb + g * 16 + l15;
        qf[g][0] = *(const bf16x8*)(qp + (long)row * 64 + 8 * l4);
        qf[g][1] = *(const bf16x8*)(qp + (long)row * 64 + 32 + 8 * l4);
    }

    f32x4 o[2][4], osum[2];
#pragma unroll
    for (int g = 0; g < 2; ++g) {
        osum[g] = f32x4{0.f, 0.f, 0.f, 0.f};
#pragma unroll
        for (int ns = 0; ns < 4; ++ns) o[g][ns] = f32x4{0.f, 0.f, 0.f, 0.f};
    }
    float m[2] = {-1e30f, -1e30f};

    bf16x8 onesB;
#pragma unroll
    for (int j = 0; j < 8; ++j) onesB[j] = (bf16_t)1.0f;

    auto STAGE = [&](int tidx, int buf) {
        int kts = tidx < 2 * qt ? tidx : tidx + 2;
        int k0s = kts << 6;
        char* Kd = (char*)Ksh[buf];
        char* Vd = (char*)Vsh[buf];
#pragma unroll
        for (int c = 0; c < 2; ++c) {
            int idx2 = t + 256 * c;
            int row = idx2 >> 3, part = idx2 & 7;
            int sw = 8 * (part ^ (row & 7));
            gload_lds16(kp + (long)(k0s + row) * 64 + sw, Kd + idx2 * 16);
            gload_lds16(vp + (long)row * S_ + k0s + sw, Vd + idx2 * 16);
        }
    };

    STAGE(0, 0);
    asm volatile("s_waitcnt vmcnt(0)" ::: "memory");  // drain qf + tile0 (one-time)

    for (int idx = 0; idx < 62; ++idx) {
        int cur = idx & 1;
        if (idx < 61) {
            STAGE(idx + 1, cur ^ 1);
            asm volatile("s_waitcnt vmcnt(4)" ::: "memory");  // tile idx landed
        } else {
            asm volatile("s_waitcnt vmcnt(0)" ::: "memory");
        }
        __builtin_amdgcn_s_barrier();
        __builtin_amdgcn_sched_barrier(0);

        int kt = idx < 2 * qt ? idx : idx + 2;
        int k0 = kt << 6;
        int dk = kt - 2 * qt;
        bool maskt = (dk == -2) || (dk == -1) || (dk == 2) || (dk == 3);
        const char* Kb = (const char*)Ksh[cur];
        const char* Vb = (const char*)Vsh[cur];

        // QK^T swapped: S'[key=16ks+4*l4+r][q=l15]; K fragments shared across g
        f32x4 s0[4], s1[4];
#pragma unroll
        for (int ks = 0; ks < 4; ++ks) { s0[ks] = f32x4{0,0,0,0}; s1[ks] = f32x4{0,0,0,0}; }
#pragma unroll
        for (int ks = 0; ks < 4; ++ks) {
            int row = ks * 16 + l15;
            const char* kro = Kb + row * 128;
            int sw = (row & 7) << 4;
#pragma unroll
            for (int kk = 0; kk < 2; ++kk) {
                bf16x8 kf = *(const bf16x8*)(kro + ((16 * (kk * 4 + l4)) ^ sw));
                s0[ks] = __builtin_amdgcn_mfma_f32_16x16x32_bf16(kf, qf[0][kk], s0[ks], 0, 0, 0);
                s1[ks] = __builtin_amdgcn_mfma_f32_16x16x32_bf16(kf, qf[1][kk], s1[ks], 0, 0, 0);
            }
        }

#pragma unroll
        for (int g = 0; g < 2; ++g) {
            f32x4* sg = g ? s1 : s0;
            if (maskt) {
                int qg = wqb + g * 16 + l15;
#pragma unroll
                for (int ks = 0; ks < 4; ++ks) {
                    int kb_ = k0 + ks * 16 + l4 * 4;
#pragma unroll
                    for (int r = 0; r < 4; ++r) {
                        int dd = qg - (kb_ + r); int ad = dd < 0 ? -dd : dd;
                        if (ad <= WINDOW_) sg[ks][r] = -1e30f;
                    }
                }
            }
            // lane-local row max (q = l15), reduce across l4 groups
            float lm = -1e30f;
#pragma unroll
            for (int ks = 0; ks < 4; ++ks) {
                float a = fmaxf(fmaxf(sg[ks][0], sg[ks][1]), fmaxf(sg[ks][2], sg[ks][3]));
                lm = fmaxf(lm, a);
            }
            lm = fmaxf(lm, __shfl_xor(lm, 16));
            lm = fmaxf(lm, __shfl_xor(lm, 32));
            if (__any(lm > m[g] + THR)) {   // rare after first tile
                float mn = fmaxf(m[g], lm);
                float f = exp2f(m[g] - mn);
                m[g] = mn;
#pragma unroll
                for (int r = 0; r < 4; ++r) {
                    float fr = __shfl(f, l4 * 4 + r);
                    osum[g][r] *= fr;
#pragma unroll
                    for (int ns = 0; ns < 4; ++ns) o[g][ns][r] *= fr;
                }
            }
#pragma unroll
            for (int ks = 0; ks < 4; ++ks)
#pragma unroll
                for (int r = 0; r < 4; ++r)
                    sg[ks][r] = exp2f(sg[ks][r] - m[g]);

            // pack P into permuted-slot A-fragments (lane-local):
            // slot 8*l4+{0..3} <- keys 32c+4*l4+{0..3}, slot 8*l4+{4..7} <- keys 32c+16+4*l4+{0..3}
            bf16x8 pa[2];
#pragma unroll
            for (int c = 0; c < 2; ++c) {
                pa[c][0] = (bf16_t)sg[2*c][0];   pa[c][1] = (bf16_t)sg[2*c][1];
                pa[c][2] = (bf16_t)sg[2*c][2];   pa[c][3] = (bf16_t)sg[2*c][3];
                pa[c][4] = (bf16_t)sg[2*c+1][0]; pa[c][5] = (bf16_t)sg[2*c+1][1];
                pa[c][6] = (bf16_t)sg[2*c+1][2]; pa[c][7] = (bf16_t)sg[2*c+1][3];
            }
            // row-sum via mfma (B = ones): osum row = q-offset, all cols equal
#pragma unroll
            for (int c = 0; c < 2; ++c)
                osum[g] = __builtin_amdgcn_mfma_f32_16x16x32_bf16(pa[c], onesB, osum[g], 0, 0, 0);
            // PV: V pre-permuted -> contiguous b128 B-fragments
#pragma unroll
            for (int ns = 0; ns < 4; ++ns) {
                int drow = ns * 16 + l15;
                const char* vro = Vb + drow * 128;
                int sw = (drow & 7) << 4;
#pragma unroll
                for (int c = 0; c < 2; ++c) {
                    bf16x8 vf = *(const bf16x8*)(vro + ((64 * c + 16 * l4) ^ sw));
                    o[g][ns] = __builtin_amdgcn_mfma_f32_16x16x32_bf16(pa[c], vf, o[g][ns], 0, 0, 0);
                }
            }
        }
        __builtin_amdgcn_sched_barrier(0);
        __builtin_amdgcn_s_barrier();
    }

    // finalize + write [B,S,E] bf16 (osum row-aligned with o: no shfl needed)
#pragma unroll
    for (int g = 0; g < 2; ++g) {
#pragma unroll
        for (int r = 0; r < 4; ++r) {
            float ir = 1.0f / osum[g][r];
            int srow = wqb + g * 16 + l4 * 4 + r;
#pragma unroll
            for (int ns = 0; ns < 4; ++ns) {
                int e = h * 64 + ns * 16 + l15;
                ao[((long)b * S_ + srow) * E_ + e] = (bf16_t)(o[g][ns][r] * ir);
            }
        }
    }
}

extern "C" void kernel_launch(void* const* d_in, const int* in_sizes, int n_in,
                              void* d_out, int out_size, void* d_ws, size_t ws_size,
                              hipStream_t stream) {
    const float* x     = (const float*)d_in[0];
    const float* w_in  = (const float*)d_in[1];
    const float* b_in  = (const float*)d_in[2];
    const float* w_out = (const float*)d_in[3];
    const float* b_out = (const float*)d_in[4];
    float* out = (float*)d_out;

    char* ws = (char*)d_ws;
    bf16_t* xb  = (bf16_t*)(ws + 0);          // 12582912 (reused as attn-out)
    bf16_t* wib = (bf16_t*)(ws + 12582912);   // 3538944
    bf16_t* wob = (bf16_t*)(ws + 16121856);   // 1179648
    bf16_t* qb  = (bf16_t*)(ws + 17301504);   // 12582912
    bf16_t* kb  = (bf16_t*)(ws + 29884416);   // 12582912
    bf16_t* vtb = (bf16_t*)(ws + 42467328);   // 12582912
    bf16_t* ao  = xb;

    k_cvt<<<6144, 256, 0, stream>>>(x, xb, 6291456);
    k_cvt<<<1728, 256, 0, stream>>>(w_in, wib, 1769472);
    k_cvt<<<576, 256, 0, stream>>>(w_out, wob, 589824);

    // QKV projection: M=8192, N=2304, K=768 (v written pre-transposed + pre-permuted)
    k_gemm<0><<<64 * 18, 256, 0, stream>>>(xb, wib, b_in, qb, kb, vtb, nullptr,
                                           8192, 2304, 768, 64);
    k_attn<<<24 * 32, 256, 0, stream>>>(qb, kb, vtb, ao);
    // out projection: M=8192, N=768, K=768
    k_gemm<1><<<64 * 6, 256, 0, stream>>>(ao, wob, b_out, nullptr, nullptr, nullptr, out,
                                          8192, 768, 768, 64);
}

// Round 7
// 266.595 us; speedup vs baseline: 2.2634x; 1.1437x over previous
//
#include <hip/hip_runtime.h>
#include <hip/hip_bf16.h>
#include <stdint.h>

typedef __bf16 bf16_t;
typedef __bf16 bf16x8 __attribute__((ext_vector_type(8)));
typedef __bf16 bf16x4v __attribute__((ext_vector_type(4)));
typedef float f32x4 __attribute__((ext_vector_type(4)));

#define DEV __device__ __forceinline__

static constexpr int B_ = 2, S_ = 4096, E_ = 768, H_ = 12, D_ = 64;
static constexpr int WINDOW_ = 128;
static constexpr float QSCALE = 0.125f * 1.44269504088896f;  // fold log2(e): softmax via exp2
static constexpr float THR = 11.5f;                          // defer-max threshold (log2 domain)

// ---------- async 16B global -> LDS ----------
DEV void gload_lds16(const void* g, void* l) {
    __builtin_amdgcn_global_load_lds(
        (const __attribute__((address_space(1))) uint32_t*)g,
        (__attribute__((address_space(3))) uint32_t*)l, 16, 0, 0);
}

// ---------- fp32 -> bf16 convert ----------
__global__ void k_cvt(const float* __restrict__ in, bf16_t* __restrict__ out, int n) {
    int i = (blockIdx.x * blockDim.x + threadIdx.x) * 4;
    if (i < n) {
        float4 v = *(const float4*)(in + i);
        bf16x4v o;
        o[0] = (bf16_t)v.x; o[1] = (bf16_t)v.y; o[2] = (bf16_t)v.z; o[3] = (bf16_t)v.w;
        *(bf16x4v*)(out + i) = o;
    }
}

// ---------- NT GEMM: C[m][n] = sum_k A[m][k] * Bw[n][k] + bias[n] ----------
// EPI 0: q (scaled, exp2-domain) / k into [B,H,S,D]; v into vt [B,H,D,S] with keys
//        pre-permuted within 32-groups to match the PV A-fragment slot order.
// EPI 1: fp32 output [M][N]
template<int EPI>
__global__ void k_gemm(const bf16_t* __restrict__ A, const bf16_t* __restrict__ Bw,
                       const float* __restrict__ bias,
                       bf16_t* __restrict__ qb, bf16_t* __restrict__ kb, bf16_t* __restrict__ vtb,
                       float* __restrict__ outf,
                       int M, int N, int K, int mtiles) {
    __shared__ bf16_t As[128 * 64];
    __shared__ bf16_t Bs[128 * 64];
    int bid = blockIdx.x;
    int tm = bid % mtiles, tn = bid / mtiles;
    int m0 = tm * 128, n0 = tn * 128;
    int t = threadIdx.x;
    int lane = t & 63, wid = t >> 6;
    int l15 = lane & 15, l4 = lane >> 4;
    int wm = (wid & 1) * 64, wn = (wid >> 1) * 64;

    f32x4 acc[4][4];
#pragma unroll
    for (int i = 0; i < 4; ++i)
#pragma unroll
        for (int j = 0; j < 4; ++j) acc[i][j] = f32x4{0.f, 0.f, 0.f, 0.f};

    for (int kt = 0; kt < K; kt += 64) {
        __syncthreads();
#pragma unroll
        for (int c = 0; c < 4; ++c) {
            int idx = t + 256 * c;
            int row = idx >> 3, part = idx & 7;
            int kc = 8 * (part ^ (row & 7));
            gload_lds16(A + (long)(m0 + row) * K + kt + kc, (char*)As + idx * 16);
            gload_lds16(Bw + (long)(n0 + row) * K + kt + kc, (char*)Bs + idx * 16);
        }
        __syncthreads();
#pragma unroll
        for (int kk = 0; kk < 2; ++kk) {
            bf16x8 af[4], bfr[4];
#pragma unroll
            for (int i = 0; i < 4; ++i) {
                int row = wm + i * 16 + l15;
                int off = row * 128 + ((16 * (kk * 4 + l4)) ^ ((row & 7) << 4));
                af[i] = *(const bf16x8*)((const char*)As + off);
                int rowb = wn + i * 16 + l15;
                int offb = rowb * 128 + ((16 * (kk * 4 + l4)) ^ ((rowb & 7) << 4));
                bfr[i] = *(const bf16x8*)((const char*)Bs + offb);
            }
#pragma unroll
            for (int i = 0; i < 4; ++i)
#pragma unroll
                for (int j = 0; j < 4; ++j)
                    acc[i][j] = __builtin_amdgcn_mfma_f32_16x16x32_bf16(af[i], bfr[j], acc[i][j], 0, 0, 0);
        }
    }

#pragma unroll
    for (int i = 0; i < 4; ++i) {
#pragma unroll
        for (int j = 0; j < 4; ++j) {
            int n = n0 + wn + j * 16 + l15;
            float bv = bias[n];
            int mbase = m0 + wm + i * 16 + l4 * 4;
            if (EPI == 0) {
                int sel = n / 768, nn = n % 768;
                int h = nn >> 6, d = nn & 63;
                int b = mbase >> 12, s = mbase & 4095;
                if (sel == 2) {
                    bf16x4v pk;
#pragma unroll
                    for (int r = 0; r < 4; ++r) pk[r] = (bf16_t)(acc[i][j][r] + bv);
                    // permuted position: slot(8a+j)<-key(4a+j), slot(8a+4+j)<-key(16+4a+j)
                    int pos = (s & ~31) | (((s >> 2) & 3) << 3) | (((s >> 4) & 1) << 2);
                    *(bf16x4v*)(vtb + ((long)(b * H_ + h) * D_ + d) * S_ + pos) = pk;
                } else {
                    long o = ((long)(b * H_ + h) * S_ + s) * D_ + d;
#pragma unroll
                    for (int r = 0; r < 4; ++r) {
                        float v = acc[i][j][r] + bv;
                        if (sel == 0) qb[o + (long)r * D_] = (bf16_t)(v * QSCALE);
                        else          kb[o + (long)r * D_] = (bf16_t)v;
                    }
                }
            } else {
#pragma unroll
                for (int r = 0; r < 4; ++r)
                    outf[(long)(mbase + r) * 768 + n] = acc[i][j][r] + bv;
            }
        }
    }
}

// ---------- attention: swapped QK^T, lane-local softmax, in-register P ----------
// QBLK=128 (8 waves x 16 q), KVBLK=64, double-buffered K/V, mfma row-sum.
__global__ __launch_bounds__(512, 6)
void k_attn(const bf16_t* __restrict__ q, const bf16_t* __restrict__ k,
            const bf16_t* __restrict__ vt, bf16_t* __restrict__ ao) {
    __shared__ bf16_t Ksh[2][64 * 64];   // [key][d], 128B rows, 3-bit chunk XOR
    __shared__ bf16_t Vsh[2][64 * 64];   // [d][pos], 128B rows, 3-bit chunk XOR
    int bid = blockIdx.x;
    bid = (bid & 7) * 96 + (bid >> 3);    // XCD-aware swizzle (768 = 8*96)
    int bh = bid >> 5, qt = bid & 31;
    int q0 = qt * 128;
    int b = bh / H_, h = bh % H_;
    int t = threadIdx.x, lane = t & 63, wid = t >> 6;
    int l15 = lane & 15, l4 = lane >> 4;

    const bf16_t* qp = q + (long)bh * S_ * D_;
    const bf16_t* kp = k + (long)bh * S_ * D_;
    const bf16_t* vp = vt + (long)bh * D_ * S_;
    int wq = q0 + wid * 16;              // this wave's 16 q-rows

    // Q fragments (B-operand: col=q=l15, contraction d-chunk 8*l4)
    bf16x8 qf[2];
    {
        int row = wq + l15;
        qf[0] = *(const bf16x8*)(qp + (long)row * 64 + 8 * l4);
        qf[1] = *(const bf16x8*)(qp + (long)row * 64 + 32 + 8 * l4);
    }

    f32x4 o[4], osum;
    osum = f32x4{0.f, 0.f, 0.f, 0.f};
#pragma unroll
    for (int ns = 0; ns < 4; ++ns) o[ns] = f32x4{0.f, 0.f, 0.f, 0.f};
    float m = -1e30f;

    bf16x8 onesB;
#pragma unroll
    for (int j = 0; j < 8; ++j) onesB[j] = (bf16_t)1.0f;

    // thread-constant staging bases: 512 threads, 1 K-load + 1 V-load each
    int srow = t >> 3, spart = t & 7;
    int ssw = 8 * (spart ^ (srow & 7));
    const bf16_t* kg = kp + (long)srow * 64 + ssw;   // + kts*4096 per tile
    const bf16_t* vg = vp + (long)srow * S_ + ssw;   // + kts*64 per tile
    char* Kd = (char*)Ksh + t * 16;                  // + (buf<<13)
    char* Vd = (char*)Vsh + t * 16;

    auto STAGE = [&](int kts, int buf) {
        int bo = buf << 13;
        gload_lds16(kg + ((long)kts << 12), Kd + bo);
        gload_lds16(vg + (kts << 6), Vd + bo);
    };

    STAGE(qt ? 0 : 2, 0);
    asm volatile("s_waitcnt vmcnt(0)" ::: "memory");  // drain qf + tile0 (one-time)

    for (int idx = 0; idx < 62; ++idx) {
        int cur = idx & 1;
        if (idx < 61) {
            int nk = idx + 1; nk = nk < 2 * qt ? nk : nk + 2;
            STAGE(nk, cur ^ 1);
            asm volatile("s_waitcnt vmcnt(2)" ::: "memory");  // tile idx landed
        } else {
            asm volatile("s_waitcnt vmcnt(0)" ::: "memory");
        }
        __builtin_amdgcn_s_barrier();
        __builtin_amdgcn_sched_barrier(0);

        int kt = idx < 2 * qt ? idx : idx + 2;
        int k0 = kt << 6;
        int dk = kt - 2 * qt;
        bool maskt = (dk == -2) || (dk == -1) || (dk == 2) || (dk == 3);
        const char* Kb = (const char*)Ksh + (cur << 13);
        const char* Vb = (const char*)Vsh + (cur << 13);
        int sw = (l15 & 7) << 4;

        // QK^T swapped: S'[key=16ks+4*l4+r][q=l15]
        f32x4 s[4];
#pragma unroll
        for (int ks = 0; ks < 4; ++ks) s[ks] = f32x4{0.f, 0.f, 0.f, 0.f};
#pragma unroll
        for (int ks = 0; ks < 4; ++ks) {
            const char* kro = Kb + (ks * 16 + l15) * 128;
#pragma unroll
            for (int kk = 0; kk < 2; ++kk) {
                bf16x8 kf = *(const bf16x8*)(kro + ((16 * (kk * 4 + l4)) ^ sw));
                s[ks] = __builtin_amdgcn_mfma_f32_16x16x32_bf16(kf, qf[kk], s[ks], 0, 0, 0);
            }
        }

        if (maskt) {
            int qg = wq + l15;
#pragma unroll
            for (int ks = 0; ks < 4; ++ks) {
                int kb_ = k0 + ks * 16 + l4 * 4;
#pragma unroll
                for (int r = 0; r < 4; ++r) {
                    int dd = qg - (kb_ + r); int ad = dd < 0 ? -dd : dd;
                    if (ad <= WINDOW_) s[ks][r] = -1e30f;
                }
            }
        }
        // lane-local row max (q = l15), reduce across l4 groups
        float lm = -1e30f;
#pragma unroll
        for (int ks = 0; ks < 4; ++ks) {
            float a = fmaxf(fmaxf(s[ks][0], s[ks][1]), fmaxf(s[ks][2], s[ks][3]));
            lm = fmaxf(lm, a);
        }
        lm = fmaxf(lm, __shfl_xor(lm, 16));
        lm = fmaxf(lm, __shfl_xor(lm, 32));
        if (__any(lm > m + THR)) {   // rare after first tile
            float mn = fmaxf(m, lm);
            float f = exp2f(m - mn);
            m = mn;
#pragma unroll
            for (int r = 0; r < 4; ++r) {
                float fr = __shfl(f, l4 * 4 + r);
                osum[r] *= fr;
#pragma unroll
                for (int ns = 0; ns < 4; ++ns) o[ns][r] *= fr;
            }
        }
#pragma unroll
        for (int ks = 0; ks < 4; ++ks)
#pragma unroll
            for (int r = 0; r < 4; ++r)
                s[ks][r] = exp2f(s[ks][r] - m);

        // pack P into permuted-slot A-fragments (lane-local):
        // slot 8*l4+{0..3} <- keys 32c+4*l4+{0..3}, slot 8*l4+{4..7} <- keys 32c+16+4*l4+{0..3}
        bf16x8 pa[2];
#pragma unroll
        for (int c = 0; c < 2; ++c) {
            pa[c][0] = (bf16_t)s[2*c][0];   pa[c][1] = (bf16_t)s[2*c][1];
            pa[c][2] = (bf16_t)s[2*c][2];   pa[c][3] = (bf16_t)s[2*c][3];
            pa[c][4] = (bf16_t)s[2*c+1][0]; pa[c][5] = (bf16_t)s[2*c+1][1];
            pa[c][6] = (bf16_t)s[2*c+1][2]; pa[c][7] = (bf16_t)s[2*c+1][3];
        }
        // row-sum via mfma (B = ones): osum[r] = rowsum(q = l4*4+r)
#pragma unroll
        for (int c = 0; c < 2; ++c)
            osum = __builtin_amdgcn_mfma_f32_16x16x32_bf16(pa[c], onesB, osum, 0, 0, 0);
        // PV: V pre-permuted -> contiguous b128 B-fragments
#pragma unroll
        for (int ns = 0; ns < 4; ++ns) {
            const char* vro = Vb + (ns * 16 + l15) * 128;
#pragma unroll
            for (int c = 0; c < 2; ++c) {
                bf16x8 vf = *(const bf16x8*)(vro + ((64 * c + 16 * l4) ^ sw));
                o[ns] = __builtin_amdgcn_mfma_f32_16x16x32_bf16(pa[c], vf, o[ns], 0, 0, 0);
            }
        }
        __builtin_amdgcn_sched_barrier(0);
        __builtin_amdgcn_s_barrier();
    }

    // finalize + write [B,S,E] bf16 (osum row-aligned with o: no shfl needed)
#pragma unroll
    for (int r = 0; r < 4; ++r) {
        float ir = 1.0f / osum[r];
        int srow2 = wq + l4 * 4 + r;
#pragma unroll
        for (int ns = 0; ns < 4; ++ns) {
            int e = h * 64 + ns * 16 + l15;
            ao[((long)b * S_ + srow2) * E_ + e] = (bf16_t)(o[ns][r] * ir);
        }
    }
}

extern "C" void kernel_launch(void* const* d_in, const int* in_sizes, int n_in,
                              void* d_out, int out_size, void* d_ws, size_t ws_size,
                              hipStream_t stream) {
    const float* x     = (const float*)d_in[0];
    const float* w_in  = (const float*)d_in[1];
    const float* b_in  = (const float*)d_in[2];
    const float* w_out = (const float*)d_in[3];
    const float* b_out = (const float*)d_in[4];
    float* out = (float*)d_out;

    char* ws = (char*)d_ws;
    bf16_t* xb  = (bf16_t*)(ws + 0);          // 12582912 (reused as attn-out)
    bf16_t* wib = (bf16_t*)(ws + 12582912);   // 3538944
    bf16_t* wob = (bf16_t*)(ws + 16121856);   // 1179648
    bf16_t* qb  = (bf16_t*)(ws + 17301504);   // 12582912
    bf16_t* kb  = (bf16_t*)(ws + 29884416);   // 12582912
    bf16_t* vtb = (bf16_t*)(ws + 42467328);   // 12582912
    bf16_t* ao  = xb;

    k_cvt<<<6144, 256, 0, stream>>>(x, xb, 6291456);
    k_cvt<<<1728, 256, 0, stream>>>(w_in, wib, 1769472);
    k_cvt<<<576, 256, 0, stream>>>(w_out, wob, 589824);

    // QKV projection: M=8192, N=2304, K=768 (v written pre-transposed + pre-permuted)
    k_gemm<0><<<64 * 18, 256, 0, stream>>>(xb, wib, b_in, qb, kb, vtb, nullptr,
                                           8192, 2304, 768, 64);
    k_attn<<<24 * 32, 512, 0, stream>>>(qb, kb, vtb, ao);
    // out projection: M=8192, N=768, K=768
    k_gemm<1><<<64 * 6, 256, 0, stream>>>(ao, wob, b_out, nullptr, nullptr, nullptr, out,
                                          8192, 768, 768, 64);
}

// Round 8
// 224.113 us; speedup vs baseline: 2.6924x; 1.1896x over previous
//
#include <hip/hip_runtime.h>
#include <hip/hip_bf16.h>
#include <stdint.h>

typedef __bf16 bf16_t;
typedef __bf16 bf16x8 __attribute__((ext_vector_type(8)));
typedef __bf16 bf16x4v __attribute__((ext_vector_type(4)));
typedef float f32x4 __attribute__((ext_vector_type(4)));

#define DEV __device__ __forceinline__

static constexpr int B_ = 2, S_ = 4096, E_ = 768, H_ = 12, D_ = 64;
static constexpr int WINDOW_ = 128;
static constexpr float QSCALE = 0.125f * 1.44269504088896f;  // fold log2(e): softmax via exp2
static constexpr float THR = 11.5f;                          // defer-max threshold (log2 domain)

// fast exp2: single v_exp_f32 (1-ulp; flushes large-negative to 0) vs OCML's ~15-inst path
DEV float fexp2(float x) { return __builtin_amdgcn_exp2f(x); }

// ---------- async 16B global -> LDS ----------
DEV void gload_lds16(const void* g, void* l) {
    __builtin_amdgcn_global_load_lds(
        (const __attribute__((address_space(1))) uint32_t*)g,
        (__attribute__((address_space(3))) uint32_t*)l, 16, 0, 0);
}

// ---------- fp32 -> bf16 convert ----------
__global__ void k_cvt(const float* __restrict__ in, bf16_t* __restrict__ out, int n) {
    int i = (blockIdx.x * blockDim.x + threadIdx.x) * 4;
    if (i < n) {
        float4 v = *(const float4*)(in + i);
        bf16x4v o;
        o[0] = (bf16_t)v.x; o[1] = (bf16_t)v.y; o[2] = (bf16_t)v.z; o[3] = (bf16_t)v.w;
        *(bf16x4v*)(out + i) = o;
    }
}

// ---------- NT GEMM: C[m][n] = sum_k A[m][k] * Bw[n][k] + bias[n] ----------
// EPI 0: q (scaled, exp2-domain) / k into [B,H,S,D]; v into vt [B,H,D,S] with keys
//        pre-permuted within 32-groups to match the PV A-fragment slot order.
// EPI 1: fp32 output [M][N]
template<int EPI>
__global__ void k_gemm(const bf16_t* __restrict__ A, const bf16_t* __restrict__ Bw,
                       const float* __restrict__ bias,
                       bf16_t* __restrict__ qb, bf16_t* __restrict__ kb, bf16_t* __restrict__ vtb,
                       float* __restrict__ outf,
                       int M, int N, int K, int mtiles) {
    __shared__ bf16_t As[128 * 64];
    __shared__ bf16_t Bs[128 * 64];
    int bid = blockIdx.x;
    int tm = bid % mtiles, tn = bid / mtiles;
    int m0 = tm * 128, n0 = tn * 128;
    int t = threadIdx.x;
    int lane = t & 63, wid = t >> 6;
    int l15 = lane & 15, l4 = lane >> 4;
    int wm = (wid & 1) * 64, wn = (wid >> 1) * 64;

    f32x4 acc[4][4];
#pragma unroll
    for (int i = 0; i < 4; ++i)
#pragma unroll
        for (int j = 0; j < 4; ++j) acc[i][j] = f32x4{0.f, 0.f, 0.f, 0.f};

    for (int kt = 0; kt < K; kt += 64) {
        __syncthreads();
#pragma unroll
        for (int c = 0; c < 4; ++c) {
            int idx = t + 256 * c;
            int row = idx >> 3, part = idx & 7;
            int kc = 8 * (part ^ (row & 7));
            gload_lds16(A + (long)(m0 + row) * K + kt + kc, (char*)As + idx * 16);
            gload_lds16(Bw + (long)(n0 + row) * K + kt + kc, (char*)Bs + idx * 16);
        }
        __syncthreads();
#pragma unroll
        for (int kk = 0; kk < 2; ++kk) {
            bf16x8 af[4], bfr[4];
#pragma unroll
            for (int i = 0; i < 4; ++i) {
                int row = wm + i * 16 + l15;
                int off = row * 128 + ((16 * (kk * 4 + l4)) ^ ((row & 7) << 4));
                af[i] = *(const bf16x8*)((const char*)As + off);
                int rowb = wn + i * 16 + l15;
                int offb = rowb * 128 + ((16 * (kk * 4 + l4)) ^ ((rowb & 7) << 4));
                bfr[i] = *(const bf16x8*)((const char*)Bs + offb);
            }
#pragma unroll
            for (int i = 0; i < 4; ++i)
#pragma unroll
                for (int j = 0; j < 4; ++j)
                    acc[i][j] = __builtin_amdgcn_mfma_f32_16x16x32_bf16(af[i], bfr[j], acc[i][j], 0, 0, 0);
        }
    }

#pragma unroll
    for (int i = 0; i < 4; ++i) {
#pragma unroll
        for (int j = 0; j < 4; ++j) {
            int n = n0 + wn + j * 16 + l15;
            float bv = bias[n];
            int mbase = m0 + wm + i * 16 + l4 * 4;
            if (EPI == 0) {
                int sel = n / 768, nn = n % 768;
                int h = nn >> 6, d = nn & 63;
                int b = mbase >> 12, s = mbase & 4095;
                if (sel == 2) {
                    bf16x4v pk;
#pragma unroll
                    for (int r = 0; r < 4; ++r) pk[r] = (bf16_t)(acc[i][j][r] + bv);
                    // permuted position: slot(8a+j)<-key(4a+j), slot(8a+4+j)<-key(16+4a+j)
                    int pos = (s & ~31) | (((s >> 2) & 3) << 3) | (((s >> 4) & 1) << 2);
                    *(bf16x4v*)(vtb + ((long)(b * H_ + h) * D_ + d) * S_ + pos) = pk;
                } else {
                    long o = ((long)(b * H_ + h) * S_ + s) * D_ + d;
#pragma unroll
                    for (int r = 0; r < 4; ++r) {
                        float v = acc[i][j][r] + bv;
                        if (sel == 0) qb[o + (long)r * D_] = (bf16_t)(v * QSCALE);
                        else          kb[o + (long)r * D_] = (bf16_t)v;
                    }
                }
            } else {
#pragma unroll
                for (int r = 0; r < 4; ++r)
                    outf[(long)(mbase + r) * 768 + n] = acc[i][j][r] + bv;
            }
        }
    }
}

// ---------- attention: swapped QK^T, lane-local softmax, in-register P ----------
// QBLK=128 (8 waves x 16 q), KVBLK=64, double-buffered K/V, mfma row-sum.
__global__ __launch_bounds__(512, 6)
void k_attn(const bf16_t* __restrict__ q, const bf16_t* __restrict__ k,
            const bf16_t* __restrict__ vt, bf16_t* __restrict__ ao) {
    __shared__ bf16_t Ksh[2][64 * 64];   // [key][d], 128B rows, 3-bit chunk XOR
    __shared__ bf16_t Vsh[2][64 * 64];   // [d][pos], 128B rows, 3-bit chunk XOR
    int bid = blockIdx.x;
    bid = (bid & 7) * 96 + (bid >> 3);    // XCD-aware swizzle (768 = 8*96)
    int bh = bid >> 5, qt = bid & 31;
    int q0 = qt * 128;
    int b = bh / H_, h = bh % H_;
    int t = threadIdx.x, lane = t & 63, wid = t >> 6;
    int l15 = lane & 15, l4 = lane >> 4;

    const bf16_t* qp = q + (long)bh * S_ * D_;
    const bf16_t* kp = k + (long)bh * S_ * D_;
    const bf16_t* vp = vt + (long)bh * D_ * S_;
    int wq = q0 + wid * 16;              // this wave's 16 q-rows

    // Q fragments (B-operand: col=q=l15, contraction d-chunk 8*l4)
    bf16x8 qf[2];
    {
        int row = wq + l15;
        qf[0] = *(const bf16x8*)(qp + (long)row * 64 + 8 * l4);
        qf[1] = *(const bf16x8*)(qp + (long)row * 64 + 32 + 8 * l4);
    }

    f32x4 o[4], osum;
    osum = f32x4{0.f, 0.f, 0.f, 0.f};
#pragma unroll
    for (int ns = 0; ns < 4; ++ns) o[ns] = f32x4{0.f, 0.f, 0.f, 0.f};
    float m = -1e30f;

    bf16x8 onesB;
#pragma unroll
    for (int j = 0; j < 8; ++j) onesB[j] = (bf16_t)1.0f;

    // thread-constant staging bases: 512 threads, 1 K-load + 1 V-load each
    int srow = t >> 3, spart = t & 7;
    int ssw = 8 * (spart ^ (srow & 7));
    const bf16_t* kg = kp + (long)srow * 64 + ssw;   // + kts*4096 per tile
    const bf16_t* vg = vp + (long)srow * S_ + ssw;   // + kts*64 per tile
    char* Kd = (char*)Ksh + t * 16;                  // + (buf<<13)
    char* Vd = (char*)Vsh + t * 16;

    auto STAGE = [&](int kts, int buf) {
        int bo = buf << 13;
        gload_lds16(kg + ((long)kts << 12), Kd + bo);
        gload_lds16(vg + (kts << 6), Vd + bo);
    };

    STAGE(qt ? 0 : 2, 0);
    asm volatile("s_waitcnt vmcnt(0)" ::: "memory");  // drain qf + tile0 (one-time)

    for (int idx = 0; idx < 62; ++idx) {
        int cur = idx & 1;
        if (idx < 61) {
            int nk = idx + 1; nk = nk < 2 * qt ? nk : nk + 2;
            STAGE(nk, cur ^ 1);
            asm volatile("s_waitcnt vmcnt(2)" ::: "memory");  // tile idx landed
        } else {
            asm volatile("s_waitcnt vmcnt(0)" ::: "memory");
        }
        __builtin_amdgcn_s_barrier();
        __builtin_amdgcn_sched_barrier(0);

        int kt = idx < 2 * qt ? idx : idx + 2;
        int k0 = kt << 6;
        int dk = kt - 2 * qt;
        bool maskt = (dk == -2) || (dk == -1) || (dk == 2) || (dk == 3);
        const char* Kb = (const char*)Ksh + (cur << 13);
        const char* Vb = (const char*)Vsh + (cur << 13);
        int sw = (l15 & 7) << 4;

        // QK^T swapped: S'[key=16ks+4*l4+r][q=l15]
        f32x4 s[4];
#pragma unroll
        for (int ks = 0; ks < 4; ++ks) s[ks] = f32x4{0.f, 0.f, 0.f, 0.f};
#pragma unroll
        for (int ks = 0; ks < 4; ++ks) {
            const char* kro = Kb + (ks * 16 + l15) * 128;
#pragma unroll
            for (int kk = 0; kk < 2; ++kk) {
                bf16x8 kf = *(const bf16x8*)(kro + ((16 * (kk * 4 + l4)) ^ sw));
                s[ks] = __builtin_amdgcn_mfma_f32_16x16x32_bf16(kf, qf[kk], s[ks], 0, 0, 0);
            }
        }

        if (maskt) {
            int qg = wq + l15;
#pragma unroll
            for (int ks = 0; ks < 4; ++ks) {
                int kb_ = k0 + ks * 16 + l4 * 4;
#pragma unroll
                for (int r = 0; r < 4; ++r) {
                    int dd = qg - (kb_ + r); int ad = dd < 0 ? -dd : dd;
                    if (ad <= WINDOW_) s[ks][r] = -1e30f;
                }
            }
        }
        // lane-local row max (q = l15), reduce across l4 groups
        float lm = -1e30f;
#pragma unroll
        for (int ks = 0; ks < 4; ++ks) {
            float a = fmaxf(fmaxf(s[ks][0], s[ks][1]), fmaxf(s[ks][2], s[ks][3]));
            lm = fmaxf(lm, a);
        }
        lm = fmaxf(lm, __shfl_xor(lm, 16));
        lm = fmaxf(lm, __shfl_xor(lm, 32));
        if (__any(lm > m + THR)) {   // rare after first tile
            float mn = fmaxf(m, lm);
            float f = fexp2(m - mn);
            m = mn;
#pragma unroll
            for (int r = 0; r < 4; ++r) {
                float fr = __shfl(f, l4 * 4 + r);
                osum[r] *= fr;
#pragma unroll
                for (int ns = 0; ns < 4; ++ns) o[ns][r] *= fr;
            }
        }
#pragma unroll
        for (int ks = 0; ks < 4; ++ks)
#pragma unroll
            for (int r = 0; r < 4; ++r)
                s[ks][r] = fexp2(s[ks][r] - m);

        // pack P into permuted-slot A-fragments (lane-local):
        // slot 8*l4+{0..3} <- keys 32c+4*l4+{0..3}, slot 8*l4+{4..7} <- keys 32c+16+4*l4+{0..3}
        bf16x8 pa[2];
#pragma unroll
        for (int c = 0; c < 2; ++c) {
            pa[c][0] = (bf16_t)s[2*c][0];   pa[c][1] = (bf16_t)s[2*c][1];
            pa[c][2] = (bf16_t)s[2*c][2];   pa[c][3] = (bf16_t)s[2*c][3];
            pa[c][4] = (bf16_t)s[2*c+1][0]; pa[c][5] = (bf16_t)s[2*c+1][1];
            pa[c][6] = (bf16_t)s[2*c+1][2]; pa[c][7] = (bf16_t)s[2*c+1][3];
        }
        // row-sum via mfma (B = ones): osum[r] = rowsum(q = l4*4+r)
#pragma unroll
        for (int c = 0; c < 2; ++c)
            osum = __builtin_amdgcn_mfma_f32_16x16x32_bf16(pa[c], onesB, osum, 0, 0, 0);
        // PV: V pre-permuted -> contiguous b128 B-fragments
#pragma unroll
        for (int ns = 0; ns < 4; ++ns) {
            const char* vro = Vb + (ns * 16 + l15) * 128;
#pragma unroll
            for (int c = 0; c < 2; ++c) {
                bf16x8 vf = *(const bf16x8*)(vro + ((64 * c + 16 * l4) ^ sw));
                o[ns] = __builtin_amdgcn_mfma_f32_16x16x32_bf16(pa[c], vf, o[ns], 0, 0, 0);
            }
        }
        __builtin_amdgcn_sched_barrier(0);
        __builtin_amdgcn_s_barrier();
    }

    // finalize + write [B,S,E] bf16 (osum row-aligned with o: no shfl needed)
#pragma unroll
    for (int r = 0; r < 4; ++r) {
        float ir = 1.0f / osum[r];
        int srow2 = wq + l4 * 4 + r;
#pragma unroll
        for (int ns = 0; ns < 4; ++ns) {
            int e = h * 64 + ns * 16 + l15;
            ao[((long)b * S_ + srow2) * E_ + e] = (bf16_t)(o[ns][r] * ir);
        }
    }
}

extern "C" void kernel_launch(void* const* d_in, const int* in_sizes, int n_in,
                              void* d_out, int out_size, void* d_ws, size_t ws_size,
                              hipStream_t stream) {
    const float* x     = (const float*)d_in[0];
    const float* w_in  = (const float*)d_in[1];
    const float* b_in  = (const float*)d_in[2];
    const float* w_out = (const float*)d_in[3];
    const float* b_out = (const float*)d_in[4];
    float* out = (float*)d_out;

    char* ws = (char*)d_ws;
    bf16_t* xb  = (bf16_t*)(ws + 0);          // 12582912 (reused as attn-out)
    bf16_t* wib = (bf16_t*)(ws + 12582912);   // 3538944
    bf16_t* wob = (bf16_t*)(ws + 16121856);   // 1179648
    bf16_t* qb  = (bf16_t*)(ws + 17301504);   // 12582912
    bf16_t* kb  = (bf16_t*)(ws + 29884416);   // 12582912
    bf16_t* vtb = (bf16_t*)(ws + 42467328);   // 12582912
    bf16_t* ao  = xb;

    k_cvt<<<6144, 256, 0, stream>>>(x, xb, 6291456);
    k_cvt<<<1728, 256, 0, stream>>>(w_in, wib, 1769472);
    k_cvt<<<576, 256, 0, stream>>>(w_out, wob, 589824);

    // QKV projection: M=8192, N=2304, K=768 (v written pre-transposed + pre-permuted)
    k_gemm<0><<<64 * 18, 256, 0, stream>>>(xb, wib, b_in, qb, kb, vtb, nullptr,
                                           8192, 2304, 768, 64);
    k_attn<<<24 * 32, 512, 0, stream>>>(qb, kb, vtb, ao);
    // out projection: M=8192, N=768, K=768
    k_gemm<1><<<64 * 6, 256, 0, stream>>>(ao, wob, b_out, nullptr, nullptr, nullptr, out,
                                          8192, 768, 768, 64);
}

// Round 9
// 207.706 us; speedup vs baseline: 2.9051x; 1.0790x over previous
//
#include <hip/hip_runtime.h>
#include <hip/hip_bf16.h>
#include <stdint.h>

typedef __bf16 bf16_t;
typedef __bf16 bf16x8 __attribute__((ext_vector_type(8)));
typedef __bf16 bf16x4v __attribute__((ext_vector_type(4)));
typedef float f32x4 __attribute__((ext_vector_type(4)));

#define DEV __device__ __forceinline__

static constexpr int B_ = 2, S_ = 4096, E_ = 768, H_ = 12, D_ = 64;
static constexpr int WINDOW_ = 128;
static constexpr float QSCALE = 0.125f * 1.44269504088896f;  // fold log2(e): softmax via exp2
static constexpr float THR = 11.5f;                          // defer-max threshold (log2 domain)

template<int C> struct IC { static constexpr int v = C; };

// fast exp2: single v_exp_f32 (1-ulp; flushes large-negative to 0)
DEV float fexp2(float x) { return __builtin_amdgcn_exp2f(x); }

// ---------- async 16B global -> LDS ----------
DEV void gload_lds16(const void* g, void* l) {
    __builtin_amdgcn_global_load_lds(
        (const __attribute__((address_space(1))) uint32_t*)g,
        (__attribute__((address_space(3))) uint32_t*)l, 16, 0, 0);
}

// ---------- fp32 -> bf16 convert ----------
__global__ void k_cvt(const float* __restrict__ in, bf16_t* __restrict__ out, int n) {
    int i = (blockIdx.x * blockDim.x + threadIdx.x) * 4;
    if (i < n) {
        float4 v = *(const float4*)(in + i);
        bf16x4v o;
        o[0] = (bf16_t)v.x; o[1] = (bf16_t)v.y; o[2] = (bf16_t)v.z; o[3] = (bf16_t)v.w;
        *(bf16x4v*)(out + i) = o;
    }
}

// ---------- NT GEMM: C[m][n] = sum_k A[m][k] * Bw[n][k] + bias[n] ----------
// EPI 0: q (scaled, exp2-domain) / k into [B,H,S,D]; v into vt [B,H,D,S] with keys
//        pre-permuted within 32-groups to match the PV A-fragment slot order.
// EPI 1: fp32 output [M][N]
template<int EPI>
__global__ void k_gemm(const bf16_t* __restrict__ A, const bf16_t* __restrict__ Bw,
                       const float* __restrict__ bias,
                       bf16_t* __restrict__ qb, bf16_t* __restrict__ kb, bf16_t* __restrict__ vtb,
                       float* __restrict__ outf,
                       int M, int N, int K, int mtiles) {
    __shared__ bf16_t As[128 * 64];
    __shared__ bf16_t Bs[128 * 64];
    int bid = blockIdx.x;
    int tm = bid % mtiles, tn = bid / mtiles;
    int m0 = tm * 128, n0 = tn * 128;
    int t = threadIdx.x;
    int lane = t & 63, wid = t >> 6;
    int l15 = lane & 15, l4 = lane >> 4;
    int wm = (wid & 1) * 64, wn = (wid >> 1) * 64;

    f32x4 acc[4][4];
#pragma unroll
    for (int i = 0; i < 4; ++i)
#pragma unroll
        for (int j = 0; j < 4; ++j) acc[i][j] = f32x4{0.f, 0.f, 0.f, 0.f};

    for (int kt = 0; kt < K; kt += 64) {
        __syncthreads();
#pragma unroll
        for (int c = 0; c < 4; ++c) {
            int idx = t + 256 * c;
            int row = idx >> 3, part = idx & 7;
            int kc = 8 * (part ^ (row & 7));
            gload_lds16(A + (long)(m0 + row) * K + kt + kc, (char*)As + idx * 16);
            gload_lds16(Bw + (long)(n0 + row) * K + kt + kc, (char*)Bs + idx * 16);
        }
        __syncthreads();
#pragma unroll
        for (int kk = 0; kk < 2; ++kk) {
            bf16x8 af[4], bfr[4];
#pragma unroll
            for (int i = 0; i < 4; ++i) {
                int row = wm + i * 16 + l15;
                int off = row * 128 + ((16 * (kk * 4 + l4)) ^ ((row & 7) << 4));
                af[i] = *(const bf16x8*)((const char*)As + off);
                int rowb = wn + i * 16 + l15;
                int offb = rowb * 128 + ((16 * (kk * 4 + l4)) ^ ((rowb & 7) << 4));
                bfr[i] = *(const bf16x8*)((const char*)Bs + offb);
            }
#pragma unroll
            for (int i = 0; i < 4; ++i)
#pragma unroll
                for (int j = 0; j < 4; ++j)
                    acc[i][j] = __builtin_amdgcn_mfma_f32_16x16x32_bf16(af[i], bfr[j], acc[i][j], 0, 0, 0);
        }
    }

#pragma unroll
    for (int i = 0; i < 4; ++i) {
#pragma unroll
        for (int j = 0; j < 4; ++j) {
            int n = n0 + wn + j * 16 + l15;
            float bv = bias[n];
            int mbase = m0 + wm + i * 16 + l4 * 4;
            if (EPI == 0) {
                int sel = n / 768, nn = n % 768;
                int h = nn >> 6, d = nn & 63;
                int b = mbase >> 12, s = mbase & 4095;
                if (sel == 2) {
                    bf16x4v pk;
#pragma unroll
                    for (int r = 0; r < 4; ++r) pk[r] = (bf16_t)(acc[i][j][r] + bv);
                    // permuted position: slot(8a+j)<-key(4a+j), slot(8a+4+j)<-key(16+4a+j)
                    int pos = (s & ~31) | (((s >> 2) & 3) << 3) | (((s >> 4) & 1) << 2);
                    *(bf16x4v*)(vtb + ((long)(b * H_ + h) * D_ + d) * S_ + pos) = pk;
                } else {
                    long o = ((long)(b * H_ + h) * S_ + s) * D_ + d;
#pragma unroll
                    for (int r = 0; r < 4; ++r) {
                        float v = acc[i][j][r] + bv;
                        if (sel == 0) qb[o + (long)r * D_] = (bf16_t)(v * QSCALE);
                        else          kb[o + (long)r * D_] = (bf16_t)v;
                    }
                }
            } else {
#pragma unroll
                for (int r = 0; r < 4; ++r)
                    outf[(long)(mbase + r) * 768 + n] = acc[i][j][r] + bv;
            }
        }
    }
}

// ---------- attention: swapped QK^T, lane-local softmax, in-register P ----------
// QBLK=128 (8 waves x 16 q), KVBLK=64, double-buffered K/V, mfma row-sum.
// Compile-time buffer index -> ds_read offsets fold to immediates (no per-tile addr VALU).
__global__ __launch_bounds__(512, 4)
void k_attn(const bf16_t* __restrict__ q, const bf16_t* __restrict__ k,
            const bf16_t* __restrict__ vt, bf16_t* __restrict__ ao) {
    __shared__ bf16_t Ksh[2][64 * 64];   // [key][d], 128B rows, 3-bit chunk XOR
    __shared__ bf16_t Vsh[2][64 * 64];   // [d][pos], 128B rows, 3-bit chunk XOR
    int bid = blockIdx.x;
    bid = (bid & 7) * 96 + (bid >> 3);    // XCD-aware swizzle (768 = 8*96)
    int bh = bid >> 5, qt = bid & 31;
    int q0 = qt * 128;
    int b = bh / H_, h = bh % H_;
    int t = threadIdx.x, lane = t & 63, wid = t >> 6;
    int l15 = lane & 15, l4 = lane >> 4;

    const bf16_t* qp = q + (long)bh * S_ * D_;
    const bf16_t* kp = k + (long)bh * S_ * D_;
    const bf16_t* vp = vt + (long)bh * D_ * S_;
    int wq = q0 + wid * 16;              // this wave's 16 q-rows

    // Q fragments (B-operand: col=q=l15, contraction d-chunk 8*l4)
    bf16x8 qf[2];
    {
        int row = wq + l15;
        qf[0] = *(const bf16x8*)(qp + (long)row * 64 + 8 * l4);
        qf[1] = *(const bf16x8*)(qp + (long)row * 64 + 32 + 8 * l4);
    }

    // precomputed loop-invariant LDS byte offsets (held in VGPRs)
    int sw = (l15 & 7) << 4;
    int kofs[8], vofs[8];
#pragma unroll
    for (int ks = 0; ks < 4; ++ks)
#pragma unroll
        for (int kk = 0; kk < 2; ++kk)
            kofs[ks * 2 + kk] = (ks * 16 + l15) * 128 + ((16 * (kk * 4 + l4)) ^ sw);
#pragma unroll
    for (int ns = 0; ns < 4; ++ns)
#pragma unroll
        for (int c = 0; c < 2; ++c)
            vofs[ns * 2 + c] = (ns * 16 + l15) * 128 + ((64 * c + 16 * l4) ^ sw);

    f32x4 o[4], osum;
    osum = f32x4{0.f, 0.f, 0.f, 0.f};
#pragma unroll
    for (int ns = 0; ns < 4; ++ns) o[ns] = f32x4{0.f, 0.f, 0.f, 0.f};
    float m = -1e30f;

    bf16x8 onesB;
#pragma unroll
    for (int j = 0; j < 8; ++j) onesB[j] = (bf16_t)1.0f;

    // staging bases: 512 threads, 1 K-load + 1 V-load each
    int srow = t >> 3, spart = t & 7;
    int ssw = 8 * (spart ^ (srow & 7));
    const bf16_t* kg = kp + (long)srow * 64 + ssw;   // + kts*4096 per tile
    const bf16_t* vg = vp + (long)srow * S_ + ssw;   // + kts*64 per tile
    char* Kd0 = (char*)Ksh + t * 16;
    char* Vd0 = (char*)Vsh + t * 16;
    int qg = wq + l15;
    int qt2 = 2 * qt;

    auto NK = [&](int i) { return i < qt2 ? i : i + 2; };

    auto STAGE = [&](int kts, auto bufc) {
        constexpr int buf = decltype(bufc)::v;
        gload_lds16(kg + ((long)kts << 12), Kd0 + buf * 8192);
        gload_lds16(vg + (kts << 6), Vd0 + buf * 8192);
    };

    auto body = [&](int idx, auto curc) {
        constexpr int cur = decltype(curc)::v;
        if (idx < 61) {
            STAGE(NK(idx + 1), IC<cur ^ 1>{});
            asm volatile("s_waitcnt vmcnt(2)" ::: "memory");  // tile idx landed
        } else {
            asm volatile("s_waitcnt vmcnt(0)" ::: "memory");
        }
        __builtin_amdgcn_s_barrier();
        __builtin_amdgcn_sched_barrier(0);

        int kt = NK(idx);
        int dk = kt - qt2;
        bool maskt = (dk == -2) || (dk == -1) || (dk == 2) || (dk == 3);
        const char* Kb = (const char*)&Ksh[cur][0];
        const char* Vb = (const char*)&Vsh[cur][0];

        // QK^T swapped: S'[key=16ks+4*l4+r][q=l15]
        f32x4 s[4];
#pragma unroll
        for (int ks = 0; ks < 4; ++ks) s[ks] = f32x4{0.f, 0.f, 0.f, 0.f};
#pragma unroll
        for (int ks = 0; ks < 4; ++ks)
#pragma unroll
            for (int kk = 0; kk < 2; ++kk) {
                bf16x8 kf = *(const bf16x8*)(Kb + kofs[ks * 2 + kk]);
                s[ks] = __builtin_amdgcn_mfma_f32_16x16x32_bf16(kf, qf[kk], s[ks], 0, 0, 0);
            }

        if (maskt) {
            int k0 = kt << 6;
#pragma unroll
            for (int ks = 0; ks < 4; ++ks) {
                int kb_ = k0 + ks * 16 + l4 * 4;
#pragma unroll
                for (int r = 0; r < 4; ++r) {
                    int dd = qg - (kb_ + r); int ad = dd < 0 ? -dd : dd;
                    if (ad <= WINDOW_) s[ks][r] = -1e30f;
                }
            }
        }
        // lane-local row max (q = l15): 16 values via max3 triples
        float a0 = fmaxf(fmaxf(s[0][0], s[0][1]), s[0][2]);
        float a1 = fmaxf(fmaxf(s[0][3], s[1][0]), s[1][1]);
        float a2 = fmaxf(fmaxf(s[1][2], s[1][3]), s[2][0]);
        float a3 = fmaxf(fmaxf(s[2][1], s[2][2]), s[2][3]);
        float a4 = fmaxf(fmaxf(s[3][0], s[3][1]), s[3][2]);
        float b0 = fmaxf(fmaxf(a0, a1), a2);
        float b1 = fmaxf(fmaxf(a3, a4), s[3][3]);
        float lm = fmaxf(b0, b1);
        lm = fmaxf(lm, __shfl_xor(lm, 16));
        lm = fmaxf(lm, __shfl_xor(lm, 32));
        if (__any(lm > m + THR)) {   // rare after first tile
            float mn = fmaxf(m, lm);
            float f = fexp2(m - mn);
            m = mn;
#pragma unroll
            for (int r = 0; r < 4; ++r) {
                float fr = __shfl(f, l4 * 4 + r);
                osum[r] *= fr;
#pragma unroll
                for (int ns = 0; ns < 4; ++ns) o[ns][r] *= fr;
            }
        }
#pragma unroll
        for (int ks = 0; ks < 4; ++ks)
#pragma unroll
            for (int r = 0; r < 4; ++r)
                s[ks][r] = fexp2(s[ks][r] - m);

        // pack P into permuted-slot A-fragments (lane-local):
        bf16x8 pa[2];
#pragma unroll
        for (int c = 0; c < 2; ++c) {
            pa[c][0] = (bf16_t)s[2*c][0];   pa[c][1] = (bf16_t)s[2*c][1];
            pa[c][2] = (bf16_t)s[2*c][2];   pa[c][3] = (bf16_t)s[2*c][3];
            pa[c][4] = (bf16_t)s[2*c+1][0]; pa[c][5] = (bf16_t)s[2*c+1][1];
            pa[c][6] = (bf16_t)s[2*c+1][2]; pa[c][7] = (bf16_t)s[2*c+1][3];
        }
        // row-sum via mfma (B = ones): osum[r] = rowsum(q = l4*4+r)
#pragma unroll
        for (int c = 0; c < 2; ++c)
            osum = __builtin_amdgcn_mfma_f32_16x16x32_bf16(pa[c], onesB, osum, 0, 0, 0);
        // PV: V pre-permuted -> contiguous b128 B-fragments
#pragma unroll
        for (int ns = 0; ns < 4; ++ns)
#pragma unroll
            for (int c = 0; c < 2; ++c) {
                bf16x8 vf = *(const bf16x8*)(Vb + vofs[ns * 2 + c]);
                o[ns] = __builtin_amdgcn_mfma_f32_16x16x32_bf16(pa[c], vf, o[ns], 0, 0, 0);
            }
        __builtin_amdgcn_sched_barrier(0);
        __builtin_amdgcn_s_barrier();
    };

    STAGE(qt ? 0 : 2, IC<0>{});
    asm volatile("s_waitcnt vmcnt(0)" ::: "memory");  // drain qf + tile0 (one-time)

    for (int i2 = 0; i2 < 31; ++i2) {
        body(2 * i2, IC<0>{});
        body(2 * i2 + 1, IC<1>{});
    }

    // finalize + write [B,S,E] bf16 (osum row-aligned with o: no shfl needed)
#pragma unroll
    for (int r = 0; r < 4; ++r) {
        float ir = 1.0f / osum[r];
        int srow2 = wq + l4 * 4 + r;
#pragma unroll
        for (int ns = 0; ns < 4; ++ns) {
            int e = h * 64 + ns * 16 + l15;
            ao[((long)b * S_ + srow2) * E_ + e] = (bf16_t)(o[ns][r] * ir);
        }
    }
}

extern "C" void kernel_launch(void* const* d_in, const int* in_sizes, int n_in,
                              void* d_out, int out_size, void* d_ws, size_t ws_size,
                              hipStream_t stream) {
    const float* x     = (const float*)d_in[0];
    const float* w_in  = (const float*)d_in[1];
    const float* b_in  = (const float*)d_in[2];
    const float* w_out = (const float*)d_in[3];
    const float* b_out = (const float*)d_in[4];
    float* out = (float*)d_out;

    char* ws = (char*)d_ws;
    bf16_t* xb  = (bf16_t*)(ws + 0);          // 12582912 (reused as attn-out)
    bf16_t* wib = (bf16_t*)(ws + 12582912);   // 3538944
    bf16_t* wob = (bf16_t*)(ws + 16121856);   // 1179648
    bf16_t* qb  = (bf16_t*)(ws + 17301504);   // 12582912
    bf16_t* kb  = (bf16_t*)(ws + 29884416);   // 12582912
    bf16_t* vtb = (bf16_t*)(ws + 42467328);   // 12582912
    bf16_t* ao  = xb;

    k_cvt<<<6144, 256, 0, stream>>>(x, xb, 6291456);
    k_cvt<<<1728, 256, 0, stream>>>(w_in, wib, 1769472);
    k_cvt<<<576, 256, 0, stream>>>(w_out, wob, 589824);

    // QKV projection: M=8192, N=2304, K=768 (v written pre-transposed + pre-permuted)
    k_gemm<0><<<64 * 18, 256, 0, stream>>>(xb, wib, b_in, qb, kb, vtb, nullptr,
                                           8192, 2304, 768, 64);
    k_attn<<<24 * 32, 512, 0, stream>>>(qb, kb, vtb, ao);
    // out projection: M=8192, N=768, K=768
    k_gemm<1><<<64 * 6, 256, 0, stream>>>(ao, wob, b_out, nullptr, nullptr, nullptr, out,
                                          8192, 768, 768, 64);
}

// Round 10
// 189.850 us; speedup vs baseline: 3.1783x; 1.0941x over previous
//
#include <hip/hip_runtime.h>
#include <hip/hip_bf16.h>
#include <stdint.h>

typedef __bf16 bf16_t;
typedef __bf16 bf16x8 __attribute__((ext_vector_type(8)));
typedef __bf16 bf16x4v __attribute__((ext_vector_type(4)));
typedef float f32x4 __attribute__((ext_vector_type(4)));

#define DEV __device__ __forceinline__

static constexpr int B_ = 2, S_ = 4096, E_ = 768, H_ = 12, D_ = 64;
static constexpr int WINDOW_ = 128;
static constexpr float QSCALE = 0.125f * 1.44269504088896f;  // fold log2(e): softmax via exp2

template<int C> struct IC { static constexpr int v = C; };

// fast exp2: single v_exp_f32 (1-ulp; flushes large-negative to 0)
DEV float fexp2(float x) { return __builtin_amdgcn_exp2f(x); }

// ---------- async 16B global -> LDS ----------
DEV void gload_lds16(const void* g, void* l) {
    __builtin_amdgcn_global_load_lds(
        (const __attribute__((address_space(1))) uint32_t*)g,
        (__attribute__((address_space(3))) uint32_t*)l, 16, 0, 0);
}

// ---------- fp32 -> bf16 convert ----------
__global__ void k_cvt(const float* __restrict__ in, bf16_t* __restrict__ out, int n) {
    int i = (blockIdx.x * blockDim.x + threadIdx.x) * 4;
    if (i < n) {
        float4 v = *(const float4*)(in + i);
        bf16x4v o;
        o[0] = (bf16_t)v.x; o[1] = (bf16_t)v.y; o[2] = (bf16_t)v.z; o[3] = (bf16_t)v.w;
        *(bf16x4v*)(out + i) = o;
    }
}

// ---------- NT GEMM: C[m][n] = sum_k A[m][k] * Bw[n][k] + bias[n] ----------
// EPI 0: q (scaled, exp2-domain) / k into [B,H,S,D]; v into vt [B,H,D,S] with keys
//        pre-permuted within 32-groups to match the PV A-fragment slot order.
// EPI 1: fp32 output [M][N]
template<int EPI>
__global__ void k_gemm(const bf16_t* __restrict__ A, const bf16_t* __restrict__ Bw,
                       const float* __restrict__ bias,
                       bf16_t* __restrict__ qb, bf16_t* __restrict__ kb, bf16_t* __restrict__ vtb,
                       float* __restrict__ outf,
                       int M, int N, int K, int mtiles) {
    __shared__ bf16_t As[128 * 64];
    __shared__ bf16_t Bs[128 * 64];
    int bid = blockIdx.x;
    int tm = bid % mtiles, tn = bid / mtiles;
    int m0 = tm * 128, n0 = tn * 128;
    int t = threadIdx.x;
    int lane = t & 63, wid = t >> 6;
    int l15 = lane & 15, l4 = lane >> 4;
    int wm = (wid & 1) * 64, wn = (wid >> 1) * 64;

    f32x4 acc[4][4];
#pragma unroll
    for (int i = 0; i < 4; ++i)
#pragma unroll
        for (int j = 0; j < 4; ++j) acc[i][j] = f32x4{0.f, 0.f, 0.f, 0.f};

    for (int kt = 0; kt < K; kt += 64) {
        __syncthreads();
#pragma unroll
        for (int c = 0; c < 4; ++c) {
            int idx = t + 256 * c;
            int row = idx >> 3, part = idx & 7;
            int kc = 8 * (part ^ (row & 7));
            gload_lds16(A + (long)(m0 + row) * K + kt + kc, (char*)As + idx * 16);
            gload_lds16(Bw + (long)(n0 + row) * K + kt + kc, (char*)Bs + idx * 16);
        }
        __syncthreads();
#pragma unroll
        for (int kk = 0; kk < 2; ++kk) {
            bf16x8 af[4], bfr[4];
#pragma unroll
            for (int i = 0; i < 4; ++i) {
                int row = wm + i * 16 + l15;
                int off = row * 128 + ((16 * (kk * 4 + l4)) ^ ((row & 7) << 4));
                af[i] = *(const bf16x8*)((const char*)As + off);
                int rowb = wn + i * 16 + l15;
                int offb = rowb * 128 + ((16 * (kk * 4 + l4)) ^ ((rowb & 7) << 4));
                bfr[i] = *(const bf16x8*)((const char*)Bs + offb);
            }
#pragma unroll
            for (int i = 0; i < 4; ++i)
#pragma unroll
                for (int j = 0; j < 4; ++j)
                    acc[i][j] = __builtin_amdgcn_mfma_f32_16x16x32_bf16(af[i], bfr[j], acc[i][j], 0, 0, 0);
        }
    }

#pragma unroll
    for (int i = 0; i < 4; ++i) {
#pragma unroll
        for (int j = 0; j < 4; ++j) {
            int n = n0 + wn + j * 16 + l15;
            float bv = bias[n];
            int mbase = m0 + wm + i * 16 + l4 * 4;
            if (EPI == 0) {
                int sel = n / 768, nn = n % 768;
                int h = nn >> 6, d = nn & 63;
                int b = mbase >> 12, s = mbase & 4095;
                if (sel == 2) {
                    bf16x4v pk;
#pragma unroll
                    for (int r = 0; r < 4; ++r) pk[r] = (bf16_t)(acc[i][j][r] + bv);
                    // permuted position: slot(8a+j)<-key(4a+j), slot(8a+4+j)<-key(16+4a+j)
                    int pos = (s & ~31) | (((s >> 2) & 3) << 3) | (((s >> 4) & 1) << 2);
                    *(bf16x4v*)(vtb + ((long)(b * H_ + h) * D_ + d) * S_ + pos) = pk;
                } else {
                    long o = ((long)(b * H_ + h) * S_ + s) * D_ + d;
#pragma unroll
                    for (int r = 0; r < 4; ++r) {
                        float v = acc[i][j][r] + bv;
                        if (sel == 0) qb[o + (long)r * D_] = (bf16_t)(v * QSCALE);
                        else          kb[o + (long)r * D_] = (bf16_t)v;
                    }
                }
            } else {
#pragma unroll
                for (int r = 0; r < 4; ++r)
                    outf[(long)(mbase + r) * 768 + n] = acc[i][j][r] + bv;
            }
        }
    }
}

// ---------- attention: swapped QK^T, frozen-m softmax, in-register P ----------
// QBLK=128 (8 waves x 16 q), KVBLK=64, triple-buffered K/V, ONE barrier per tile,
// -m folded into QK MFMA C-init, mfma row-sum.
__global__ __launch_bounds__(512, 6)
void k_attn(const bf16_t* __restrict__ q, const bf16_t* __restrict__ k,
            const bf16_t* __restrict__ vt, bf16_t* __restrict__ ao) {
    __shared__ bf16_t Ksh[3][4096];   // [key][d], 128B rows, 3-bit chunk XOR
    __shared__ bf16_t Vsh[3][4096];   // [d][pos], 128B rows, 3-bit chunk XOR
    int bid = blockIdx.x;
    bid = (bid & 7) * 96 + (bid >> 3);    // XCD-aware swizzle (768 = 8*96)
    int bh = bid >> 5, qt = bid & 31;
    int q0 = qt * 128;
    int b = bh / H_, h = bh % H_;
    int t = threadIdx.x, lane = t & 63, wid = t >> 6;
    int l15 = lane & 15, l4 = lane >> 4;

    const bf16_t* qp = q + (long)bh * S_ * D_;
    const bf16_t* kp = k + (long)bh * S_ * D_;
    const bf16_t* vp = vt + (long)bh * D_ * S_;
    int wq = q0 + wid * 16;              // this wave's 16 q-rows

    // Q fragments (B-operand: col=q=l15, contraction d-chunk 8*l4)
    bf16x8 qf[2];
    {
        int row = wq + l15;
        qf[0] = *(const bf16x8*)(qp + (long)row * 64 + 8 * l4);
        qf[1] = *(const bf16x8*)(qp + (long)row * 64 + 32 + 8 * l4);
    }

    // LDS fragment addressing: 2 VGPR bases + compile-time immediates
    int sw = (l15 & 7) << 4;
    int a0 = l15 * 128 + ((16 * l4) ^ sw);
    int a1 = a0 ^ 64;

    f32x4 o[4], osum;
    osum = f32x4{0.f, 0.f, 0.f, 0.f};
#pragma unroll
    for (int ns = 0; ns < 4; ++ns) o[ns] = f32x4{0.f, 0.f, 0.f, 0.f};
    float m_ = 0.f;
    f32x4 mneg4 = f32x4{0.f, 0.f, 0.f, 0.f};

    bf16x8 onesB;
#pragma unroll
    for (int j = 0; j < 8; ++j) onesB[j] = (bf16_t)1.0f;

    // staging: SGPR tile base + 32-bit per-thread offset
    int srow = t >> 3, spart = t & 7;
    int ssw = 8 * (spart ^ (srow & 7));
    int koff = srow * 64 + ssw;
    int voff = srow * S_ + ssw;
    int qt2 = 2 * qt;
    int qg = wq + l15;

    auto NK = [&](int i) { return i < qt2 ? i : i + 2; };

    auto STAGE = [&](int kts, auto bufc) {
        constexpr int buf = decltype(bufc)::v;
        gload_lds16(kp + ((long)kts << 12) + koff, (char*)Ksh + buf * 8192 + t * 16);
        gload_lds16(vp + (kts << 6) + voff, (char*)Vsh + buf * 8192 + t * 16);
    };

    auto QK = [&](auto curc, f32x4* s, f32x4 cinit) {
        constexpr int cur = decltype(curc)::v;
        const char* KL = (const char*)Ksh + cur * 8192;
#pragma unroll
        for (int ks = 0; ks < 4; ++ks) {
            bf16x8 kf0 = *(const bf16x8*)(KL + a0 + ks * 2048);
            bf16x8 kf1 = *(const bf16x8*)(KL + a1 + ks * 2048);
            s[ks] = __builtin_amdgcn_mfma_f32_16x16x32_bf16(kf0, qf[0], cinit, 0, 0, 0);
            s[ks] = __builtin_amdgcn_mfma_f32_16x16x32_bf16(kf1, qf[1], s[ks], 0, 0, 0);
        }
    };

    auto MASK = [&](int kt, f32x4* s) {
        int k0 = kt << 6;
#pragma unroll
        for (int ks = 0; ks < 4; ++ks) {
            int kb_ = k0 + ks * 16 + l4 * 4;
#pragma unroll
            for (int r = 0; r < 4; ++r) {
                int dd = qg - (kb_ + r); int ad = dd < 0 ? -dd : dd;
                if (ad <= WINDOW_) s[ks][r] = -1e30f;
            }
        }
    };

    auto TAIL = [&](auto curc, f32x4* s) {
        constexpr int cur = decltype(curc)::v;
        // pack P into permuted-slot A-fragments (lane-local)
        bf16x8 pa[2];
#pragma unroll
        for (int c = 0; c < 2; ++c) {
            pa[c][0] = (bf16_t)s[2*c][0];   pa[c][1] = (bf16_t)s[2*c][1];
            pa[c][2] = (bf16_t)s[2*c][2];   pa[c][3] = (bf16_t)s[2*c][3];
            pa[c][4] = (bf16_t)s[2*c+1][0]; pa[c][5] = (bf16_t)s[2*c+1][1];
            pa[c][6] = (bf16_t)s[2*c+1][2]; pa[c][7] = (bf16_t)s[2*c+1][3];
        }
        // row-sum via mfma (B = ones)
        osum = __builtin_amdgcn_mfma_f32_16x16x32_bf16(pa[0], onesB, osum, 0, 0, 0);
        osum = __builtin_amdgcn_mfma_f32_16x16x32_bf16(pa[1], onesB, osum, 0, 0, 0);
        // PV: V pre-permuted -> contiguous b128 B-fragments
        const char* VL = (const char*)Vsh + cur * 8192;
#pragma unroll
        for (int ns = 0; ns < 4; ++ns) {
            bf16x8 vf0 = *(const bf16x8*)(VL + a0 + ns * 2048);
            bf16x8 vf1 = *(const bf16x8*)(VL + a1 + ns * 2048);
            o[ns] = __builtin_amdgcn_mfma_f32_16x16x32_bf16(pa[0], vf0, o[ns], 0, 0, 0);
            o[ns] = __builtin_amdgcn_mfma_f32_16x16x32_bf16(pa[1], vf1, o[ns], 0, 0, 0);
        }
    };

    auto body = [&](int idx, auto curc) {
        if (idx < 61) {
            STAGE(NK(idx + 1), IC<(decltype(curc)::v + 1) % 3>{});
            asm volatile("s_waitcnt vmcnt(2)" ::: "memory");  // tile idx landed
        } else {
            asm volatile("s_waitcnt vmcnt(0)" ::: "memory");
        }
        __builtin_amdgcn_s_barrier();
        __builtin_amdgcn_sched_barrier(0);

        int kt = NK(idx);
        int dk = kt - qt2;
        f32x4 s[4];
        QK(curc, s, mneg4);            // C-init = -m: MFMA emits s_raw - m
        if (dk == -2 || dk == -1 || dk == 2 || dk == 3) MASK(kt, s);
#pragma unroll
        for (int ks = 0; ks < 4; ++ks)
#pragma unroll
            for (int r = 0; r < 4; ++r)
                s[ks][r] = fexp2(s[ks][r]);
        TAIL(curc, s);
    };

    STAGE(NK(0), IC<0>{});

    // ---- first tile: establish frozen m ----
    {
        STAGE(NK(1), IC<1>{});
        asm volatile("s_waitcnt vmcnt(2)" ::: "memory");
        __builtin_amdgcn_s_barrier();
        __builtin_amdgcn_sched_barrier(0);

        int kt = NK(0);
        int dk = kt - qt2;
        f32x4 s[4];
        QK(IC<0>{}, s, f32x4{0.f, 0.f, 0.f, 0.f});
        if (dk == -2 || dk == -1 || dk == 2 || dk == 3) MASK(kt, s);
        float lm = -1e30f;
#pragma unroll
        for (int ks = 0; ks < 4; ++ks) {
            float a = fmaxf(fmaxf(s[ks][0], s[ks][1]), fmaxf(s[ks][2], s[ks][3]));
            lm = fmaxf(lm, a);
        }
        lm = fmaxf(lm, __shfl_xor(lm, 16));
        lm = fmaxf(lm, __shfl_xor(lm, 32));
        m_ = fmaxf(lm, 0.0f);   // guard: rows fully masked in first tile
        mneg4 = f32x4{-m_, -m_, -m_, -m_};
#pragma unroll
        for (int ks = 0; ks < 4; ++ks)
#pragma unroll
            for (int r = 0; r < 4; ++r)
                s[ks][r] = fexp2(s[ks][r] - m_);
        TAIL(IC<0>{}, s);
    }

    for (int i3 = 0; i3 < 20; ++i3) {
        body(3 * i3 + 1, IC<1>{});
        body(3 * i3 + 2, IC<2>{});
        body(3 * i3 + 3, IC<0>{});
    }
    body(61, IC<1>{});

    // finalize + write [B,S,E] bf16 (osum row-aligned with o)
#pragma unroll
    for (int r = 0; r < 4; ++r) {
        float ir = 1.0f / osum[r];
        int srow2 = wq + l4 * 4 + r;
#pragma unroll
        for (int ns = 0; ns < 4; ++ns) {
            int e = h * 64 + ns * 16 + l15;
            ao[((long)b * S_ + srow2) * E_ + e] = (bf16_t)(o[ns][r] * ir);
        }
    }
}

extern "C" void kernel_launch(void* const* d_in, const int* in_sizes, int n_in,
                              void* d_out, int out_size, void* d_ws, size_t ws_size,
                              hipStream_t stream) {
    const float* x     = (const float*)d_in[0];
    const float* w_in  = (const float*)d_in[1];
    const float* b_in  = (const float*)d_in[2];
    const float* w_out = (const float*)d_in[3];
    const float* b_out = (const float*)d_in[4];
    float* out = (float*)d_out;

    char* ws = (char*)d_ws;
    bf16_t* xb  = (bf16_t*)(ws + 0);          // 12582912 (reused as attn-out)
    bf16_t* wib = (bf16_t*)(ws + 12582912);   // 3538944
    bf16_t* wob = (bf16_t*)(ws + 16121856);   // 1179648
    bf16_t* qb  = (bf16_t*)(ws + 17301504);   // 12582912
    bf16_t* kb  = (bf16_t*)(ws + 29884416);   // 12582912
    bf16_t* vtb = (bf16_t*)(ws + 42467328);   // 12582912
    bf16_t* ao  = xb;

    k_cvt<<<6144, 256, 0, stream>>>(x, xb, 6291456);
    k_cvt<<<1728, 256, 0, stream>>>(w_in, wib, 1769472);
    k_cvt<<<576, 256, 0, stream>>>(w_out, wob, 589824);

    // QKV projection: M=8192, N=2304, K=768 (v written pre-transposed + pre-permuted)
    k_gemm<0><<<64 * 18, 256, 0, stream>>>(xb, wib, b_in, qb, kb, vtb, nullptr,
                                           8192, 2304, 768, 64);
    k_attn<<<24 * 32, 512, 0, stream>>>(qb, kb, vtb, ao);
    // out projection: M=8192, N=768, K=768
    k_gemm<1><<<64 * 6, 256, 0, stream>>>(ao, wob, b_out, nullptr, nullptr, nullptr, out,
                                          8192, 768, 768, 64);
}